// Round 2
// baseline (377.133 us; speedup 1.0000x reference)
//
#include <hip/hip_runtime.h>
#include <cmath>

// ---------------------------------------------------------------------------
// CrossAttention: B=4, N=1024, C=1024, H=16, HD=64
//   q = x@Wq ; kv = k_in@Wkv ; p = softmax(q k^T /8); z = p*a; w = softmax(z)
//   out = (w@v)@Wproj + b
// Numerical design: z = p*a in [0,~0.01] => second softmax near-uniform =>
// q/k/score errors damped ~1e4x. Precision spent on: v (3-term compensated
// bf16 GEMM), PV (centered: out=(SumV + expm1(z)@v)/E), proj (3-term).
// Attn v2: no K/V LDS staging (L2-resident, direct fragment loads), score
// recompute in pass 2, expm1->poly, 8KB swizzled delta tile, 1 barrier/mt.
// ---------------------------------------------------------------------------

#define Bb 4
#define Nn 1024
#define Cc 1024
#define Hh 16
#define HD 64
static constexpr float SCALE = 0.125f;

typedef unsigned short u16;
typedef short bf16x8 __attribute__((ext_vector_type(8)));
typedef float f32x4 __attribute__((ext_vector_type(4)));
typedef __attribute__((address_space(1))) const void* gptr_t;
typedef __attribute__((address_space(3))) void* lptr_t;

__device__ __forceinline__ u16 f2b(float f) {
  union { float f; unsigned u; } x; x.f = f;
  unsigned u = x.u;
  return (u16)((u + 0x7FFFu + ((u >> 16) & 1u)) >> 16);
}
__device__ __forceinline__ float b2f(u16 h) {
  union { unsigned u; float f; } x; x.u = ((unsigned)h) << 16;
  return x.f;
}

// ---------------- prep: bf16 + hi/lo splits, transposed weights -------------
__global__ __launch_bounds__(256) void prep_big(
    const float* __restrict__ x, const float* __restrict__ kin,
    const float* __restrict__ af,
    u16* __restrict__ xh, u16* __restrict__ kinh, u16* __restrict__ kinl,
    u16* __restrict__ ab) {
  int i = blockIdx.x * 256 + threadIdx.x;              // 4M threads exact
  xh[i] = f2b(x[i]);
  float v = kin[i];
  u16 hh = f2b(v);
  kinh[i] = hh;
  kinl[i] = f2b(v - b2f(hh));
  ab[i] = f2b(af[i]);                                  // B*N*N == B*N*C == 4M
}

__global__ __launch_bounds__(256) void prep_w(
    const float* __restrict__ Wq, const float* __restrict__ Wkv, const float* __restrict__ Wp,
    u16* __restrict__ WqT, u16* __restrict__ WkT, u16* __restrict__ WvTh, u16* __restrict__ WvTl,
    u16* __restrict__ WpTh, u16* __restrict__ WpTl) {
  int j = blockIdx.x * 256 + threadIdx.x;              // 1M threads; j=(o,i)
  int o = j >> 10, i = j & 1023;
  WqT[j] = f2b(Wq[(size_t)i * 1024 + o]);
  WkT[j] = f2b(Wkv[(size_t)i * 2048 + o]);
  float wv = Wkv[(size_t)i * 2048 + 1024 + o];
  u16 hh = f2b(wv);
  WvTh[j] = hh; WvTl[j] = f2b(wv - b2f(hh));
  float wp = Wp[(size_t)i * 1024 + o];
  hh = f2b(wp);
  WpTh[j] = hh; WpTl[j] = f2b(wp - b2f(hh));
}

// ---------------- plain bf16 GEMM (A[M][K] x Bt[N][K]) -> q_b/k_b bf16 ------
__global__ __launch_bounds__(256) void gemm_qk(
    const u16* __restrict__ A, const u16* __restrict__ Bt, u16* __restrict__ dsth) {
  constexpr int K = 1024;
  __shared__ u16 As[4096];
  __shared__ u16 Bs[4096];
  const int tid = threadIdx.x;
  const int wave = tid >> 6, lane = tid & 63;
  const int l15 = lane & 15, l4 = lane >> 4;
  const int m0 = blockIdx.x * 128, n0 = blockIdx.y * 128;
  const int wr = wave >> 1, wc = wave & 1;
  const int srow = wave * 32 + (lane >> 2);
  const int scol = (lane & 3) * 8;
  f32x4 acc[4][4] = {};
  const u16* gA = A + (size_t)(m0 + srow) * K + scol;
  const u16* gB = Bt + (size_t)(n0 + srow) * K + scol;
  u16* lA0 = As + (wave * 2 + 0) * 512;
  u16* lA1 = As + (wave * 2 + 1) * 512;
  u16* lB0 = Bs + (wave * 2 + 0) * 512;
  u16* lB1 = Bs + (wave * 2 + 1) * 512;
  for (int kt = 0; kt < K; kt += 32) {
    __syncthreads();
    __builtin_amdgcn_global_load_lds((gptr_t)(gA + kt),            (lptr_t)lA0, 16, 0, 0);
    __builtin_amdgcn_global_load_lds((gptr_t)(gA + kt + 16 * K),   (lptr_t)lA1, 16, 0, 0);
    __builtin_amdgcn_global_load_lds((gptr_t)(gB + kt),            (lptr_t)lB0, 16, 0, 0);
    __builtin_amdgcn_global_load_lds((gptr_t)(gB + kt + 16 * K),   (lptr_t)lB1, 16, 0, 0);
    __syncthreads();
    bf16x8 af[4], bf_[4];
    #pragma unroll
    for (int i = 0; i < 4; ++i)
      af[i] = *(const bf16x8*)(As + (wr * 64 + i * 16 + l15) * 32 + l4 * 8);
    #pragma unroll
    for (int i = 0; i < 4; ++i)
      bf_[i] = *(const bf16x8*)(Bs + (wc * 64 + i * 16 + l15) * 32 + l4 * 8);
    #pragma unroll
    for (int mi = 0; mi < 4; ++mi)
      #pragma unroll
      for (int ni = 0; ni < 4; ++ni)
        acc[mi][ni] = __builtin_amdgcn_mfma_f32_16x16x32_bf16(af[mi], bf_[ni], acc[mi][ni], 0, 0, 0);
  }
  #pragma unroll
  for (int mi = 0; mi < 4; ++mi) {
    #pragma unroll
    for (int ni = 0; ni < 4; ++ni) {
      #pragma unroll
      for (int r = 0; r < 4; ++r) {
        const int grow = m0 + wr * 64 + mi * 16 + l4 * 4 + r;    // b*N+n
        const int gcol = n0 + wc * 64 + ni * 16 + l15;           // h*64+d
        const int bb = grow >> 10, n = grow & 1023, hh = gcol >> 6, d = gcol & 63;
        dsth[(((size_t)(bb * Hh + hh)) * Nn + n) * HD + d] = f2b(acc[mi][ni][r]);
      }
    }
  }
}

// ------------- fused 3-term compensated GEMM: Ah*Bh + Ah*Bl + Al*Bh ---------
template <int EPI>
__global__ __launch_bounds__(256) void gemm3_bt(
    const u16* __restrict__ Ah, const u16* __restrict__ Al,
    const u16* __restrict__ Bh, const u16* __restrict__ Bl,
    float* __restrict__ dstf, u16* __restrict__ dsth, const float* __restrict__ bias) {
  constexpr int K = 1024;
  __shared__ u16 sAh[4096], sAl[4096], sBh[4096], sBl[4096];
  const int tid = threadIdx.x;
  const int wave = tid >> 6, lane = tid & 63;
  const int l15 = lane & 15, l4 = lane >> 4;
  const int m0 = blockIdx.x * 128, n0 = blockIdx.y * 128;
  const int wr = wave >> 1, wc = wave & 1;
  const int srow = wave * 32 + (lane >> 2);
  const int scol = (lane & 3) * 8;
  f32x4 acc[4][4] = {};
  const u16* gAh = Ah + (size_t)(m0 + srow) * K + scol;
  const u16* gAl = Al + (size_t)(m0 + srow) * K + scol;
  const u16* gBh = Bh + (size_t)(n0 + srow) * K + scol;
  const u16* gBl = Bl + (size_t)(n0 + srow) * K + scol;
  const int eoff = (wave * 2) * 512;
  for (int kt = 0; kt < K; kt += 32) {
    __syncthreads();
    __builtin_amdgcn_global_load_lds((gptr_t)(gAh + kt),          (lptr_t)(sAh + eoff), 16, 0, 0);
    __builtin_amdgcn_global_load_lds((gptr_t)(gAh + kt + 16 * K), (lptr_t)(sAh + eoff + 512), 16, 0, 0);
    __builtin_amdgcn_global_load_lds((gptr_t)(gAl + kt),          (lptr_t)(sAl + eoff), 16, 0, 0);
    __builtin_amdgcn_global_load_lds((gptr_t)(gAl + kt + 16 * K), (lptr_t)(sAl + eoff + 512), 16, 0, 0);
    __builtin_amdgcn_global_load_lds((gptr_t)(gBh + kt),          (lptr_t)(sBh + eoff), 16, 0, 0);
    __builtin_amdgcn_global_load_lds((gptr_t)(gBh + kt + 16 * K), (lptr_t)(sBh + eoff + 512), 16, 0, 0);
    __builtin_amdgcn_global_load_lds((gptr_t)(gBl + kt),          (lptr_t)(sBl + eoff), 16, 0, 0);
    __builtin_amdgcn_global_load_lds((gptr_t)(gBl + kt + 16 * K), (lptr_t)(sBl + eoff + 512), 16, 0, 0);
    __syncthreads();
    bf16x8 fah[4], fal[4], fbh[4], fbl[4];
    #pragma unroll
    for (int i = 0; i < 4; ++i) {
      const int ra = (wr * 64 + i * 16 + l15) * 32 + l4 * 8;
      const int rb = (wc * 64 + i * 16 + l15) * 32 + l4 * 8;
      fah[i] = *(const bf16x8*)(sAh + ra);
      fal[i] = *(const bf16x8*)(sAl + ra);
      fbh[i] = *(const bf16x8*)(sBh + rb);
      fbl[i] = *(const bf16x8*)(sBl + rb);
    }
    #pragma unroll
    for (int mi = 0; mi < 4; ++mi) {
      #pragma unroll
      for (int ni = 0; ni < 4; ++ni) {
        acc[mi][ni] = __builtin_amdgcn_mfma_f32_16x16x32_bf16(fah[mi], fbh[ni], acc[mi][ni], 0, 0, 0);
        acc[mi][ni] = __builtin_amdgcn_mfma_f32_16x16x32_bf16(fah[mi], fbl[ni], acc[mi][ni], 0, 0, 0);
        acc[mi][ni] = __builtin_amdgcn_mfma_f32_16x16x32_bf16(fal[mi], fbh[ni], acc[mi][ni], 0, 0, 0);
      }
    }
  }
  #pragma unroll
  for (int mi = 0; mi < 4; ++mi) {
    #pragma unroll
    for (int ni = 0; ni < 4; ++ni) {
      #pragma unroll
      for (int r = 0; r < 4; ++r) {
        const int grow = m0 + wr * 64 + mi * 16 + l4 * 4 + r;
        const int gcol = n0 + wc * 64 + ni * 16 + l15;
        const float v = acc[mi][ni][r];
        if constexpr (EPI == 0) {
          const int bb = grow >> 10, n = grow & 1023, hh = gcol >> 6, d = gcol & 63;
          const size_t o = (((size_t)(bb * Hh + hh)) * HD + d) * Nn + n;
          dstf[o] = v;
          dsth[o] = f2b(v);
        } else {
          dstf[(size_t)grow * Cc + gcol] = v + bias[gcol];
        }
      }
    }
  }
}

// ---------------- SumV[b][h][d] = sum_m v[m][d] (fp32) ----------------------
__global__ __launch_bounds__(256) void sumv_kernel(const float* __restrict__ vtf,
                                                   float* __restrict__ sv) {
  const int bh = blockIdx.x >> 2, d16 = blockIdx.x & 3;
  const int t = threadIdx.x;
  const int d = d16 * 16 + (t >> 4), part = t & 15;
  const float* src = vtf + ((size_t)bh * HD + d) * Nn + part * 64;
  float s = 0.f;
  #pragma unroll
  for (int i = 0; i < 64; i += 4) {
    f32x4 v = *(const f32x4*)(src + i);
    s += v[0] + v[1] + v[2] + v[3];
  }
  s += __shfl_xor(s, 1, 64);
  s += __shfl_xor(s, 2, 64);
  s += __shfl_xor(s, 4, 64);
  s += __shfl_xor(s, 8, 64);
  if (part == 0) sv[(size_t)bh * HD + d] = s;
}

// ---------------- fused double-softmax attention (v2) -----------------------
// block = (b,h,qt): 16 q rows, 4 waves. No K/V LDS (direct global fragment
// loads, L2-resident). Pass 1: L = sum exp(s/8). Pass 2: recompute s,
// delta = expm1(exp(s/8 - lnL)*a) ~ poly, transpose via 8KB swizzled LDS
// tile (double-buffered, 1 barrier per mt), PV MFMA accumulate.
__global__ __launch_bounds__(256) void attn_kernel(
    const u16* __restrict__ qb, const u16* __restrict__ kb,
    const u16* __restrict__ vtb, const float* __restrict__ sv,
    const u16* __restrict__ ab, u16* __restrict__ aoh, u16* __restrict__ aol) {
  __shared__ u16 d_lds[2][2048];      // [16 q][128 m] bf16, XOR-swizzled
  __shared__ float Lp_lds[4][16];
  __shared__ float Ep_lds[4][16];
  __shared__ float L_arr[16];

  const int tid = threadIdx.x;
  const int wave = tid >> 6, lane = tid & 63;
  const int l15 = lane & 15, l4 = lane >> 4;
  // XCD-chunked swizzle (4096 % 8 == 0 -> bijective): XCD gets 8 contiguous bh
  const int bid = (blockIdx.x & 7) * 512 + (blockIdx.x >> 3);
  const int qt = bid & 63, h = (bid >> 6) & 15, b = bid >> 10;
  const size_t bh = (size_t)(b * Hh + h);
  const u16* qg = qb + (bh * Nn + qt * 16) * HD;
  const u16* kg = kb + bh * Nn * HD;
  const u16* vg = vtb + bh * HD * Nn;
  const u16* ag = ab + ((size_t)b * Nn + qt * 16) * Nn;

  // q A-fragments, held in registers for both passes
  bf16x8 qf0 = *(const bf16x8*)(qg + l15 * HD + l4 * 8);
  bf16x8 qf1 = *(const bf16x8*)(qg + l15 * HD + 32 + l4 * 8);

  // ---- pass 1: L[q] = sum_m exp(s/8). No barriers, no LDS. ----
  float Lp[4] = {0.f, 0.f, 0.f, 0.f};
  for (int mt = 0; mt < 8; ++mt) {
    #pragma unroll
    for (int cf = 0; cf < 2; ++cf) {
      const int m = mt * 128 + wave * 32 + cf * 16 + l15;
      const u16* kr = kg + (size_t)m * HD + l4 * 8;
      bf16x8 k0 = *(const bf16x8*)kr;
      bf16x8 k1 = *(const bf16x8*)(kr + 32);
      f32x4 acc = {0.f, 0.f, 0.f, 0.f};
      acc = __builtin_amdgcn_mfma_f32_16x16x32_bf16(qf0, k0, acc, 0, 0, 0);
      acc = __builtin_amdgcn_mfma_f32_16x16x32_bf16(qf1, k1, acc, 0, 0, 0);
      #pragma unroll
      for (int r = 0; r < 4; ++r) Lp[r] += __expf(acc[r] * SCALE);
    }
  }
  #pragma unroll
  for (int r = 0; r < 4; ++r) {
    float v = Lp[r];
    v += __shfl_xor(v, 1, 64); v += __shfl_xor(v, 2, 64);
    v += __shfl_xor(v, 4, 64); v += __shfl_xor(v, 8, 64);
    if (l15 == 0) Lp_lds[wave][l4 * 4 + r] = v;
  }
  __syncthreads();
  if (tid < 16) L_arr[tid] = Lp_lds[0][tid] + Lp_lds[1][tid] + Lp_lds[2][tid] + Lp_lds[3][tid];
  __syncthreads();
  float nlnL[4];
  #pragma unroll
  for (int r = 0; r < 4; ++r) nlnL[r] = -__logf(L_arr[l4 * 4 + r]);

  // ---- pass 2: recompute s, delta=poly_expm1(p*a), transpose, PV ----
  float ep[4] = {0.f, 0.f, 0.f, 0.f};
  f32x4 oacc = {0.f, 0.f, 0.f, 0.f};
  for (int mt = 0; mt < 8; ++mt) {
    u16* dbuf = d_lds[mt & 1];
    #pragma unroll
    for (int cf = 0; cf < 2; ++cf) {
      const int mloc = wave * 32 + cf * 16 + l15;
      const int m = mt * 128 + mloc;
      const u16* kr = kg + (size_t)m * HD + l4 * 8;
      bf16x8 k0 = *(const bf16x8*)kr;
      bf16x8 k1 = *(const bf16x8*)(kr + 32);
      f32x4 acc = {0.f, 0.f, 0.f, 0.f};
      acc = __builtin_amdgcn_mfma_f32_16x16x32_bf16(qf0, k0, acc, 0, 0, 0);
      acc = __builtin_amdgcn_mfma_f32_16x16x32_bf16(qf1, k1, acc, 0, 0, 0);
      #pragma unroll
      for (int r = 0; r < 4; ++r) {
        const int q = l4 * 4 + r;
        const float p = __expf(fmaf(acc[r], SCALE, nlnL[r]));
        const float av = b2f(ag[(size_t)q * Nn + m]);
        const float z = p * av;
        const float t = fmaf(z, 0.16666667f, 0.5f);     // expm1 ~ z + z^2/2 + z^3/6
        const float dl = fmaf(z * z, t, z);
        ep[r] += dl;
        dbuf[q * 128 + (mloc ^ ((q & 7) << 3))] = f2b(dl);
      }
    }
    // prefetch V fragments before the barrier (overlaps other waves' scores)
    bf16x8 vf[4];
    #pragma unroll
    for (int kb_ = 0; kb_ < 4; ++kb_) {
      vf[kb_] = *(const bf16x8*)(vg + (size_t)(wave * 16 + l15) * Nn + mt * 128 + kb_ * 32 + l4 * 8);
    }
    __syncthreads();   // dbuf ready; double-buffer makes 1 barrier/mt safe
    #pragma unroll
    for (int kb_ = 0; kb_ < 4; ++kb_) {
      bf16x8 df = *(const bf16x8*)(dbuf + l15 * 128 + ((kb_ * 32 + l4 * 8) ^ ((l15 & 7) << 3)));
      oacc = __builtin_amdgcn_mfma_f32_16x16x32_bf16(df, vf[kb_], oacc, 0, 0, 0);
    }
  }

  // ---- Ep reduce + epilogue ----
  #pragma unroll
  for (int r = 0; r < 4; ++r) {
    float v = ep[r];
    v += __shfl_xor(v, 1, 64); v += __shfl_xor(v, 2, 64);
    v += __shfl_xor(v, 4, 64); v += __shfl_xor(v, 8, 64);
    if (l15 == 0) Ep_lds[wave][l4 * 4 + r] = v;
  }
  __syncthreads();
  {
    const int d = wave * 16 + l15;
    const float svd = sv[bh * HD + d];
    #pragma unroll
    for (int r = 0; r < 4; ++r) {
      const int row = l4 * 4 + r;
      const float E = 1024.0f + Ep_lds[0][row] + Ep_lds[1][row] + Ep_lds[2][row] + Ep_lds[3][row];
      const float ov = (svd + oacc[r]) / E;
      const int n = qt * 16 + row;
      const size_t oi = ((size_t)b * Nn + n) * Cc + h * HD + d;
      const u16 hi = f2b(ov);
      aoh[oi] = hi;
      aol[oi] = f2b(ov - b2f(hi));
    }
  }
}

// ---------------------------------------------------------------------------
extern "C" void kernel_launch(void* const* d_in, const int* in_sizes, int n_in,
                              void* d_out, int out_size, void* d_ws, size_t ws_size,
                              hipStream_t stream) {
  (void)in_sizes; (void)n_in; (void)out_size; (void)ws_size;
  const float* x   = (const float*)d_in[0];
  const float* kin = (const float*)d_in[1];
  const float* af  = (const float*)d_in[2];
  const float* Wq  = (const float*)d_in[3];
  const float* Wkv = (const float*)d_in[4];
  const float* Wp  = (const float*)d_in[5];
  const float* bp  = (const float*)d_in[6];
  float* out = (float*)d_out;

  char* w = (char*)d_ws;
  auto take = [&](size_t bytes) { char* p = w; w += (bytes + 255) & ~(size_t)255; return p; };
  u16* WqT   = (u16*)take(2097152);
  u16* WkT   = (u16*)take(2097152);
  u16* WvTh  = (u16*)take(2097152);
  u16* WvTl  = (u16*)take(2097152);
  u16* WpTh  = (u16*)take(2097152);
  u16* WpTl  = (u16*)take(2097152);
  u16* xh    = (u16*)take(8388608);
  u16* kinh  = (u16*)take(8388608);
  u16* kinl  = (u16*)take(8388608);
  u16* ab    = (u16*)take(8388608);
  u16* qb    = (u16*)take(8388608);
  u16* kb    = (u16*)take(8388608);
  u16* vtb   = (u16*)take(8388608);
  float* vtf = (float*)take(16777216);
  float* sv  = (float*)take(16384);
  u16* aoh   = (u16*)take(8388608);
  u16* aol   = (u16*)take(8388608);

  prep_big<<<dim3(16384), dim3(256), 0, stream>>>(x, kin, af, xh, kinh, kinl, ab);
  prep_w<<<dim3(4096), dim3(256), 0, stream>>>(Wq, Wkv, Wp, WqT, WkT, WvTh, WvTl, WpTh, WpTl);

  dim3 gg(32, 8), blk(256);
  gemm_qk<<<gg, blk, 0, stream>>>(xh, WqT, qb);
  gemm_qk<<<gg, blk, 0, stream>>>(kinh, WkT, kb);
  gemm3_bt<0><<<gg, blk, 0, stream>>>(kinh, kinl, WvTh, WvTl, vtf, vtb, nullptr);
  sumv_kernel<<<dim3(256), dim3(256), 0, stream>>>(vtf, sv);
  attn_kernel<<<dim3(4096), dim3(256), 0, stream>>>(qb, kb, vtb, sv, ab, aoh, aol);
  gemm3_bt<1><<<gg, blk, 0, stream>>>(aoh, aol, WpTh, WpTl, out, nullptr, bp);
}

// Round 3
// 285.108 us; speedup vs baseline: 1.3228x; 1.3228x over previous
//
#include <hip/hip_runtime.h>
#include <cmath>

// ---------------------------------------------------------------------------
// CrossAttention: B=4, N=1024, C=1024, H=16, HD=64
//   q = x@Wq ; kv = k_in@Wkv ; p = softmax(q k^T /8); z = p*a; w = softmax(z)
//   out = (w@v)@Wproj + b
// Numerical design: z = p*a in [0,~0.01] => second softmax near-uniform =>
// q/k/score errors damped ~1e4x. Precision on: v (3-term bf16 GEMM),
// PV (centered: out=(SumV + expm1(z)@v)/E), proj (3-term).
// v3: attn 32q/block + software-pipelined loads + coalesced a; 64x128 GEMM
// tiles (2-4 blocks/CU); merged k+v GEMM; tiled transpose prep.
// ---------------------------------------------------------------------------

#define Bb 4
#define Nn 1024
#define Cc 1024
#define Hh 16
#define HD 64
static constexpr float SCALE = 0.125f;

typedef unsigned short u16;
typedef short bf16x8 __attribute__((ext_vector_type(8)));
typedef float f32x4 __attribute__((ext_vector_type(4)));
typedef unsigned short u16x4 __attribute__((ext_vector_type(4)));
typedef __attribute__((address_space(1))) const void* gptr_t;
typedef __attribute__((address_space(3))) void* lptr_t;

__device__ __forceinline__ u16 f2b(float f) {
  union { float f; unsigned u; } x; x.f = f;
  unsigned u = x.u;
  return (u16)((u + 0x7FFFu + ((u >> 16) & 1u)) >> 16);
}
__device__ __forceinline__ float b2f(u16 h) {
  union { unsigned u; float f; } x; x.u = ((unsigned)h) << 16;
  return x.f;
}

// ---------------- prep: bf16 + hi/lo splits of big activations --------------
__global__ __launch_bounds__(256) void prep_big(
    const float* __restrict__ x, const float* __restrict__ kin,
    const float* __restrict__ af,
    u16* __restrict__ xh, u16* __restrict__ kinh, u16* __restrict__ kinl,
    u16* __restrict__ ab) {
  int i = blockIdx.x * 256 + threadIdx.x;              // 4M threads exact
  xh[i] = f2b(x[i]);
  float v = kin[i];
  u16 hh = f2b(v);
  kinh[i] = hh;
  kinl[i] = f2b(v - b2f(hh));
  ab[i] = f2b(af[i]);                                  // B*N*N == 4M
}

// ---------------- tiled weight transposes (coalesced both sides) ------------
// Wq (1024^2, h only), Wkv (1024x2048 -> 2048x1024, h+l), Wp (1024^2, h+l)
__global__ __launch_bounds__(256) void prep_wt(
    const float* __restrict__ Wq, const float* __restrict__ Wkv,
    const float* __restrict__ Wp,
    u16* __restrict__ WqT, u16* __restrict__ WkvTh, u16* __restrict__ WkvTl,
    u16* __restrict__ WpTh, u16* __restrict__ WpTl) {
  __shared__ float tile[64][65];
  int id = blockIdx.x;
  const float* src; int srcld; u16 *dh, *dl; int ot0, it0;
  if (id < 256)      { src = Wq;  srcld = 1024; dh = WqT;   dl = nullptr;
                       ot0 = (id >> 4) * 64; it0 = (id & 15) * 64; }
  else if (id < 768) { id -= 256; src = Wkv; srcld = 2048; dh = WkvTh; dl = WkvTl;
                       ot0 = (id >> 4) * 64; it0 = (id & 15) * 64; }
  else               { id -= 768; src = Wp;  srcld = 1024; dh = WpTh;  dl = WpTl;
                       ot0 = (id >> 4) * 64; it0 = (id & 15) * 64; }
  const int tr = threadIdx.x >> 4;          // 0..15
  const int tc = (threadIdx.x & 15) * 4;    // 0..60
  #pragma unroll
  for (int rr = 0; rr < 4; ++rr) {
    const int r = rr * 16 + tr;
    f32x4 v = *(const f32x4*)&src[(size_t)(it0 + r) * srcld + ot0 + tc];
    tile[r][tc] = v[0]; tile[r][tc + 1] = v[1];
    tile[r][tc + 2] = v[2]; tile[r][tc + 3] = v[3];
  }
  __syncthreads();
  #pragma unroll
  for (int rr = 0; rr < 4; ++rr) {
    const int o = rr * 16 + tr;
    u16x4 hv, lv;
    #pragma unroll
    for (int j = 0; j < 4; ++j) {
      float w = tile[tc + j][o];
      u16 hh = f2b(w);
      hv[j] = hh; lv[j] = f2b(w - b2f(hh));
    }
    const size_t off = (size_t)(ot0 + o) * 1024 + it0 + tc;
    *(u16x4*)(dh + off) = hv;
    if (dl) *(u16x4*)(dl + off) = lv;
  }
}

// ---------------- plain bf16 GEMM 64x128 tile -> q bf16 ---------------------
__global__ __launch_bounds__(256) void gemm_q(
    const u16* __restrict__ A, const u16* __restrict__ Bt, u16* __restrict__ dsth) {
  constexpr int K = 1024;
  __shared__ u16 As[64 * 32];
  __shared__ u16 Bs[128 * 32];
  const int tid = threadIdx.x;
  const int wave = tid >> 6, lane = tid & 63;
  const int l15 = lane & 15, l4 = lane >> 4;
  const int m0 = blockIdx.x * 64, n0 = blockIdx.y * 128;
  const int wr = wave >> 1, wc = wave & 1;
  const int srow = tid >> 2, scol = (tid & 3) * 8;
  f32x4 acc[2][4] = {};
  const u16* gA  = A  + (size_t)(m0 + srow) * K + scol;
  const u16* gB0 = Bt + (size_t)(n0 + srow) * K + scol;
  const u16* gB1 = Bt + (size_t)(n0 + 64 + srow) * K + scol;
  for (int kt = 0; kt < K; kt += 32) {
    __syncthreads();
    __builtin_amdgcn_global_load_lds((gptr_t)(gA  + kt), (lptr_t)(As + wave * 512), 16, 0, 0);
    __builtin_amdgcn_global_load_lds((gptr_t)(gB0 + kt), (lptr_t)(Bs + wave * 512), 16, 0, 0);
    __builtin_amdgcn_global_load_lds((gptr_t)(gB1 + kt), (lptr_t)(Bs + 2048 + wave * 512), 16, 0, 0);
    __syncthreads();
    bf16x8 af[2], bf_[4];
    #pragma unroll
    for (int i = 0; i < 2; ++i)
      af[i] = *(const bf16x8*)(As + (wr * 32 + i * 16 + l15) * 32 + l4 * 8);
    #pragma unroll
    for (int i = 0; i < 4; ++i)
      bf_[i] = *(const bf16x8*)(Bs + (wc * 64 + i * 16 + l15) * 32 + l4 * 8);
    #pragma unroll
    for (int mi = 0; mi < 2; ++mi)
      #pragma unroll
      for (int ni = 0; ni < 4; ++ni)
        acc[mi][ni] = __builtin_amdgcn_mfma_f32_16x16x32_bf16(af[mi], bf_[ni], acc[mi][ni], 0, 0, 0);
  }
  #pragma unroll
  for (int mi = 0; mi < 2; ++mi)
    #pragma unroll
    for (int ni = 0; ni < 4; ++ni)
      #pragma unroll
      for (int r = 0; r < 4; ++r) {
        const int grow = m0 + wr * 32 + mi * 16 + l4 * 4 + r;   // b*N+n
        const int gcol = n0 + wc * 64 + ni * 16 + l15;          // h*64+d
        const int bb = grow >> 10, n = grow & 1023, hh = gcol >> 6, d = gcol & 63;
        dsth[(((size_t)(bb * Hh + hh)) * Nn + n) * HD + d] = f2b(acc[mi][ni][r]);
      }
}

// ------------- 3-term compensated GEMM 64x128: Ah*Bh + Ah*Bl + Al*Bh --------
// EPI 0: KV (N=2048): n0<1024 -> k bf16 [b,h,n,d]; else v -> vtf+vtb [bh,d,n]
// EPI 1: proj -> d_out f32 + bias
template <int EPI>
__global__ __launch_bounds__(256) void gemm3(
    const u16* __restrict__ Ah, const u16* __restrict__ Al,
    const u16* __restrict__ Bh, const u16* __restrict__ Bl,
    float* __restrict__ dstf, u16* __restrict__ dsth_k, u16* __restrict__ dsth_v,
    const float* __restrict__ bias) {
  constexpr int K = 1024;
  __shared__ u16 sAh[64 * 32], sAl[64 * 32];
  __shared__ u16 sBh[128 * 32], sBl[128 * 32];
  const int tid = threadIdx.x;
  const int wave = tid >> 6, lane = tid & 63;
  const int l15 = lane & 15, l4 = lane >> 4;
  const int m0 = blockIdx.x * 64, n0 = blockIdx.y * 128;
  const int wr = wave >> 1, wc = wave & 1;
  const int srow = tid >> 2, scol = (tid & 3) * 8;
  f32x4 acc[2][4] = {};
  const u16* gAh = Ah + (size_t)(m0 + srow) * K + scol;
  const u16* gAl = Al + (size_t)(m0 + srow) * K + scol;
  const u16* gBh0 = Bh + (size_t)(n0 + srow) * K + scol;
  const u16* gBh1 = Bh + (size_t)(n0 + 64 + srow) * K + scol;
  const u16* gBl0 = Bl + (size_t)(n0 + srow) * K + scol;
  const u16* gBl1 = Bl + (size_t)(n0 + 64 + srow) * K + scol;
  for (int kt = 0; kt < K; kt += 32) {
    __syncthreads();
    __builtin_amdgcn_global_load_lds((gptr_t)(gAh  + kt), (lptr_t)(sAh + wave * 512), 16, 0, 0);
    __builtin_amdgcn_global_load_lds((gptr_t)(gAl  + kt), (lptr_t)(sAl + wave * 512), 16, 0, 0);
    __builtin_amdgcn_global_load_lds((gptr_t)(gBh0 + kt), (lptr_t)(sBh + wave * 512), 16, 0, 0);
    __builtin_amdgcn_global_load_lds((gptr_t)(gBh1 + kt), (lptr_t)(sBh + 2048 + wave * 512), 16, 0, 0);
    __builtin_amdgcn_global_load_lds((gptr_t)(gBl0 + kt), (lptr_t)(sBl + wave * 512), 16, 0, 0);
    __builtin_amdgcn_global_load_lds((gptr_t)(gBl1 + kt), (lptr_t)(sBl + 2048 + wave * 512), 16, 0, 0);
    __syncthreads();
    bf16x8 fah[2], fal[2], fbh[4], fbl[4];
    #pragma unroll
    for (int i = 0; i < 2; ++i) {
      const int ra = (wr * 32 + i * 16 + l15) * 32 + l4 * 8;
      fah[i] = *(const bf16x8*)(sAh + ra);
      fal[i] = *(const bf16x8*)(sAl + ra);
    }
    #pragma unroll
    for (int i = 0; i < 4; ++i) {
      const int rb = (wc * 64 + i * 16 + l15) * 32 + l4 * 8;
      fbh[i] = *(const bf16x8*)(sBh + rb);
      fbl[i] = *(const bf16x8*)(sBl + rb);
    }
    #pragma unroll
    for (int mi = 0; mi < 2; ++mi)
      #pragma unroll
      for (int ni = 0; ni < 4; ++ni) {
        acc[mi][ni] = __builtin_amdgcn_mfma_f32_16x16x32_bf16(fah[mi], fbh[ni], acc[mi][ni], 0, 0, 0);
        acc[mi][ni] = __builtin_amdgcn_mfma_f32_16x16x32_bf16(fah[mi], fbl[ni], acc[mi][ni], 0, 0, 0);
        acc[mi][ni] = __builtin_amdgcn_mfma_f32_16x16x32_bf16(fal[mi], fbh[ni], acc[mi][ni], 0, 0, 0);
      }
  }
  #pragma unroll
  for (int mi = 0; mi < 2; ++mi)
    #pragma unroll
    for (int ni = 0; ni < 4; ++ni)
      #pragma unroll
      for (int r = 0; r < 4; ++r) {
        const int grow = m0 + wr * 32 + mi * 16 + l4 * 4 + r;
        const int gcol = n0 + wc * 64 + ni * 16 + l15;
        const float v = acc[mi][ni][r];
        if constexpr (EPI == 0) {
          const int bb = grow >> 10, n = grow & 1023;
          if (n0 < 1024) {          // k columns (uniform per block)
            const int hh = gcol >> 6, d = gcol & 63;
            dsth_k[(((size_t)(bb * Hh + hh)) * Nn + n) * HD + d] = f2b(v);
          } else {                  // v columns
            const int col = gcol - 1024;
            const int hh = col >> 6, d = col & 63;
            const size_t o = (((size_t)(bb * Hh + hh)) * HD + d) * Nn + n;
            dstf[o] = v;
            dsth_v[o] = f2b(v);
          }
        } else {
          dstf[(size_t)grow * Cc + gcol] = v + bias[gcol];
        }
      }
}

// ---------------- SumV[b][h][d] = sum_m v[m][d] (fp32) ----------------------
__global__ __launch_bounds__(256) void sumv_kernel(const float* __restrict__ vtf,
                                                   float* __restrict__ sv) {
  const int bh = blockIdx.x >> 2, d16 = blockIdx.x & 3;
  const int t = threadIdx.x;
  const int d = d16 * 16 + (t >> 4), part = t & 15;
  const float* src = vtf + ((size_t)bh * HD + d) * Nn + part * 64;
  float s = 0.f;
  #pragma unroll
  for (int i = 0; i < 64; i += 4) {
    f32x4 v = *(const f32x4*)(src + i);
    s += v[0] + v[1] + v[2] + v[3];
  }
  s += __shfl_xor(s, 1, 64);
  s += __shfl_xor(s, 2, 64);
  s += __shfl_xor(s, 4, 64);
  s += __shfl_xor(s, 8, 64);
  if (part == 0) sv[(size_t)bh * HD + d] = s;
}

// ---------------- fused double-softmax attention (v3) -----------------------
// block = 32 q-rows (2 q-tiles), 4 waves, grid 2048. Direct global K/V/a
// loads, software-pipelined: loads for next phase issued at top of current.
// Pass 1: L. Pass 2 per mt: A{scores->p, LDS} B{delta=poly(p*a)} C{PV MFMA}.
__global__ __launch_bounds__(256, 4) void attn_kernel(
    const u16* __restrict__ qb, const u16* __restrict__ kb,
    const u16* __restrict__ vtb, const float* __restrict__ sv,
    const u16* __restrict__ ab, u16* __restrict__ aoh, u16* __restrict__ aol) {
  __shared__ u16 p_lds[2][32 * 128];        // 16 KB, XOR-swizzled cols
  __shared__ float Lp_lds[4][32];
  __shared__ float L_arr[32];
  __shared__ float Ep_arr[32];

  const int tid = threadIdx.x;
  const int wave = tid >> 6, lane = tid & 63;
  const int l15 = lane & 15, l4 = lane >> 4;
  const int bid = (blockIdx.x & 7) * 256 + (blockIdx.x >> 3);   // XCD chunking
  const int qt = bid & 31, h = (bid >> 5) & 15, b = bid >> 9;
  const size_t bh = (size_t)(b * Hh + h);
  const u16* qg = qb + (bh * Nn + qt * 32) * HD;
  const u16* kg = kb + bh * Nn * HD;
  const u16* vg = vtb + bh * HD * Nn;

  // q fragments for both q-tiles
  bf16x8 qf[2][2];
  #pragma unroll
  for (int t2 = 0; t2 < 2; ++t2)
    #pragma unroll
    for (int ks = 0; ks < 2; ++ks)
      qf[t2][ks] = *(const bf16x8*)(qg + (t2 * 16 + l15) * HD + ks * 32 + l4 * 8);

  // ---- pass 1: L[q] = sum_m exp(s/8), prefetched K chain ----
  float Lp[2][4] = {};
  const u16* kbase = kg + (size_t)(wave * 32 + l15) * HD + l4 * 8;
  bf16x8 kc0 = *(const bf16x8*)kbase;
  bf16x8 kc1 = *(const bf16x8*)(kbase + 32);
  #pragma unroll
  for (int j = 0; j < 16; ++j) {
    bf16x8 kn0, kn1;
    if (j < 15) {
      const u16* kr = kbase + (size_t)((((j + 1) >> 1) << 7) + (((j + 1) & 1) << 4)) * HD;
      kn0 = *(const bf16x8*)kr;
      kn1 = *(const bf16x8*)(kr + 32);
    }
    f32x4 s0 = {}, s1 = {};
    s0 = __builtin_amdgcn_mfma_f32_16x16x32_bf16(qf[0][0], kc0, s0, 0, 0, 0);
    s0 = __builtin_amdgcn_mfma_f32_16x16x32_bf16(qf[0][1], kc1, s0, 0, 0, 0);
    s1 = __builtin_amdgcn_mfma_f32_16x16x32_bf16(qf[1][0], kc0, s1, 0, 0, 0);
    s1 = __builtin_amdgcn_mfma_f32_16x16x32_bf16(qf[1][1], kc1, s1, 0, 0, 0);
    #pragma unroll
    for (int r = 0; r < 4; ++r) {
      Lp[0][r] += __expf(s0[r] * SCALE);
      Lp[1][r] += __expf(s1[r] * SCALE);
    }
    kc0 = kn0; kc1 = kn1;
  }
  #pragma unroll
  for (int t2 = 0; t2 < 2; ++t2)
    #pragma unroll
    for (int r = 0; r < 4; ++r) {
      float v = Lp[t2][r];
      v += __shfl_xor(v, 1, 64); v += __shfl_xor(v, 2, 64);
      v += __shfl_xor(v, 4, 64); v += __shfl_xor(v, 8, 64);
      if (l15 == 0) Lp_lds[wave][t2 * 16 + l4 * 4 + r] = v;
    }
  __syncthreads();
  if (tid < 32) L_arr[tid] = Lp_lds[0][tid] + Lp_lds[1][tid] + Lp_lds[2][tid] + Lp_lds[3][tid];
  __syncthreads();
  float nl[2][4];
  #pragma unroll
  for (int t2 = 0; t2 < 2; ++t2)
    #pragma unroll
    for (int r = 0; r < 4; ++r)
      nl[t2][r] = -__logf(L_arr[t2 * 16 + l4 * 4 + r]);

  // ---- pass 2 ----
  const int qB = tid >> 3;                   // 0..31 (fixed per thread)
  const int mB = (tid & 7) << 4;
  const u16* agq = ab + ((size_t)b * Nn + qt * 32 + qB) * Nn + mB;
  const int swzB = (qB & 7) << 3;
  float eacc = 0.f;
  f32x4 oacc[2] = {};

  bf16x8 kcur0 = *(const bf16x8*)kbase;                 // mt=0, cf=0
  bf16x8 kcur1 = *(const bf16x8*)(kbase + 32);
  bf16x8 kcur2 = *(const bf16x8*)(kbase + 16 * HD);     // mt=0, cf=1
  bf16x8 kcur3 = *(const bf16x8*)(kbase + 16 * HD + 32);

  for (int mt = 0; mt < 8; ++mt) {
    u16* pb = p_lds[mt & 1];
    // --- issue all loads consumed later this iteration / next iteration ---
    bf16x8 kn0, kn1, kn2, kn3;
    if (mt < 7) {
      const u16* kr = kbase + (size_t)(mt + 1) * 128 * HD;
      kn0 = *(const bf16x8*)kr;
      kn1 = *(const bf16x8*)(kr + 32);
      kn2 = *(const bf16x8*)(kr + 16 * HD);
      kn3 = *(const bf16x8*)(kr + 16 * HD + 32);
    }
    bf16x8 av0 = *(const bf16x8*)(agq + (mt << 7));
    bf16x8 av1 = *(const bf16x8*)(agq + (mt << 7) + 8);
    bf16x8 vf[4];
    #pragma unroll
    for (int k2 = 0; k2 < 4; ++k2)
      vf[k2] = *(const bf16x8*)(vg + (size_t)(wave * 16 + l15) * Nn + (mt << 7) + k2 * 32 + l4 * 8);

    // --- stage A: scores -> p (bf16) into swizzled LDS ---
    #pragma unroll
    for (int cf = 0; cf < 2; ++cf) {
      bf16x8 ka = cf ? kcur2 : kcur0;
      bf16x8 kbv = cf ? kcur3 : kcur1;
      f32x4 s0 = {}, s1 = {};
      s0 = __builtin_amdgcn_mfma_f32_16x16x32_bf16(qf[0][0], ka, s0, 0, 0, 0);
      s0 = __builtin_amdgcn_mfma_f32_16x16x32_bf16(qf[0][1], kbv, s0, 0, 0, 0);
      s1 = __builtin_amdgcn_mfma_f32_16x16x32_bf16(qf[1][0], ka, s1, 0, 0, 0);
      s1 = __builtin_amdgcn_mfma_f32_16x16x32_bf16(qf[1][1], kbv, s1, 0, 0, 0);
      const int mloc = wave * 32 + cf * 16 + l15;
      #pragma unroll
      for (int r = 0; r < 4; ++r) {
        const int q0 = l4 * 4 + r;
        const int q1 = 16 + q0;
        pb[q0 * 128 + (mloc ^ ((q0 & 7) << 3))] = f2b(__expf(fmaf(s0[r], SCALE, nl[0][r])));
        pb[q1 * 128 + (mloc ^ ((q1 & 7) << 3))] = f2b(__expf(fmaf(s1[r], SCALE, nl[1][r])));
      }
    }
    kcur0 = kn0; kcur1 = kn1; kcur2 = kn2; kcur3 = kn3;
    __syncthreads();   // p ready

    // --- stage B: delta = expm1(p*a) ~ poly, rewrite in place ---
    {
      u16* prow = pb + qB * 128;
      bf16x8 p0 = *(const bf16x8*)(prow + (mB ^ swzB));
      bf16x8 p1 = *(const bf16x8*)(prow + ((mB + 8) ^ swzB));
      bf16x8 d0, d1;
      #pragma unroll
      for (int j = 0; j < 8; ++j) {
        const float z = b2f((u16)p0[j]) * b2f((u16)av0[j]);
        const float t = fmaf(z, 0.16666667f, 0.5f);
        const float dl = fmaf(z * z, t, z);
        eacc += dl;
        d0[j] = (short)f2b(dl);
      }
      #pragma unroll
      for (int j = 0; j < 8; ++j) {
        const float z = b2f((u16)p1[j]) * b2f((u16)av1[j]);
        const float t = fmaf(z, 0.16666667f, 0.5f);
        const float dl = fmaf(z * z, t, z);
        eacc += dl;
        d1[j] = (short)f2b(dl);
      }
      *(bf16x8*)(prow + (mB ^ swzB)) = d0;
      *(bf16x8*)(prow + ((mB + 8) ^ swzB)) = d1;
    }
    __syncthreads();   // deltas ready

    // --- stage C: PV MFMA ---
    #pragma unroll
    for (int t2 = 0; t2 < 2; ++t2)
      #pragma unroll
      for (int k2 = 0; k2 < 4; ++k2) {
        const int row = t2 * 16 + l15;
        bf16x8 df = *(const bf16x8*)(pb + row * 128 + ((k2 * 32 + l4 * 8) ^ ((row & 7) << 3)));
        oacc[t2] = __builtin_amdgcn_mfma_f32_16x16x32_bf16(df, vf[k2], oacc[t2], 0, 0, 0);
      }
  }

  // ---- Ep reduce + epilogue ----
  eacc += __shfl_xor(eacc, 1, 64);
  eacc += __shfl_xor(eacc, 2, 64);
  eacc += __shfl_xor(eacc, 4, 64);
  if ((tid & 7) == 0) Ep_arr[qB] = eacc;
  __syncthreads();
  {
    const int d = wave * 16 + l15;
    const float svd = sv[bh * HD + d];
    #pragma unroll
    for (int t2 = 0; t2 < 2; ++t2)
      #pragma unroll
      for (int r = 0; r < 4; ++r) {
        const int row = t2 * 16 + l4 * 4 + r;
        const float E = 1024.0f + Ep_arr[row];
        const float ov = (svd + oacc[t2][r]) / E;
        const int n = qt * 32 + row;
        const size_t oi = ((size_t)b * Nn + n) * Cc + h * HD + d;
        const u16 hi = f2b(ov);
        aoh[oi] = hi;
        aol[oi] = f2b(ov - b2f(hi));
      }
  }
}

// ---------------------------------------------------------------------------
extern "C" void kernel_launch(void* const* d_in, const int* in_sizes, int n_in,
                              void* d_out, int out_size, void* d_ws, size_t ws_size,
                              hipStream_t stream) {
  (void)in_sizes; (void)n_in; (void)out_size; (void)ws_size;
  const float* x   = (const float*)d_in[0];
  const float* kin = (const float*)d_in[1];
  const float* af  = (const float*)d_in[2];
  const float* Wq  = (const float*)d_in[3];
  const float* Wkv = (const float*)d_in[4];
  const float* Wp  = (const float*)d_in[5];
  const float* bp  = (const float*)d_in[6];
  float* out = (float*)d_out;

  char* w = (char*)d_ws;
  auto take = [&](size_t bytes) { char* p = w; w += (bytes + 255) & ~(size_t)255; return p; };
  u16* WqT    = (u16*)take(2097152);
  u16* WkvTh  = (u16*)take(4194304);
  u16* WkvTl  = (u16*)take(4194304);
  u16* WpTh   = (u16*)take(2097152);
  u16* WpTl   = (u16*)take(2097152);
  u16* xh     = (u16*)take(8388608);
  u16* kinh   = (u16*)take(8388608);
  u16* kinl   = (u16*)take(8388608);
  u16* ab     = (u16*)take(8388608);
  u16* qb     = (u16*)take(8388608);
  u16* kb     = (u16*)take(8388608);
  u16* vtb    = (u16*)take(8388608);
  float* vtf  = (float*)take(16777216);
  float* sv   = (float*)take(16384);
  u16* aoh    = (u16*)take(8388608);
  u16* aol    = (u16*)take(8388608);

  prep_big<<<dim3(16384), dim3(256), 0, stream>>>(x, kin, af, xh, kinh, kinl, ab);
  prep_wt<<<dim3(1024), dim3(256), 0, stream>>>(Wq, Wkv, Wp, WqT, WkvTh, WkvTl, WpTh, WpTl);

  gemm_q<<<dim3(64, 8), dim3(256), 0, stream>>>(xh, WqT, qb);
  gemm3<0><<<dim3(64, 16), dim3(256), 0, stream>>>(kinh, kinl, WkvTh, WkvTl, vtf, kb, vtb, nullptr);
  sumv_kernel<<<dim3(256), dim3(256), 0, stream>>>(vtf, sv);
  attn_kernel<<<dim3(2048), dim3(256), 0, stream>>>(qb, kb, vtb, sv, ab, aoh, aol);
  gemm3<1><<<dim3(64, 8), dim3(256), 0, stream>>>(aoh, aol, WpTh, WpTl, out, nullptr, nullptr, bp);
}

// Round 5
// 242.505 us; speedup vs baseline: 1.5552x; 1.1757x over previous
//
#include <hip/hip_runtime.h>
#include <cmath>

// ---------------------------------------------------------------------------
// CrossAttention: B=4, N=1024, C=1024, H=16, HD=64
//   q = x@Wq ; kv = k_in@Wkv ; p = softmax(q k^T /8); z = p*a; w = softmax(z)
//   out = (w@v)@Wproj + b
// v5 (bisect round): round-3 kernels VERBATIM (prep, gemm_q, sumv, attn),
// with gemm3<0>/<1> reduced to plain bf16 (gemm_kv / gemm_proj) by mechanical
// deletion of the Al/Bl terms. Tests the plain-bf16 numerics hypothesis in
// isolation after round-4's unlocalized failure.
// ---------------------------------------------------------------------------

#define Bb 4
#define Nn 1024
#define Cc 1024
#define Hh 16
#define HD 64
static constexpr float SCALE = 0.125f;

typedef unsigned short u16;
typedef short bf16x8 __attribute__((ext_vector_type(8)));
typedef float f32x4 __attribute__((ext_vector_type(4)));
typedef unsigned short u16x4 __attribute__((ext_vector_type(4)));
typedef __attribute__((address_space(1))) const void* gptr_t;
typedef __attribute__((address_space(3))) void* lptr_t;

__device__ __forceinline__ u16 f2b(float f) {
  union { float f; unsigned u; } x; x.f = f;
  unsigned u = x.u;
  return (u16)((u + 0x7FFFu + ((u >> 16) & 1u)) >> 16);
}
__device__ __forceinline__ float b2f(u16 h) {
  union { unsigned u; float f; } x; x.u = ((unsigned)h) << 16;
  return x.f;
}

// ---------------- prep: bf16 + hi/lo splits of big activations (r3) ---------
__global__ __launch_bounds__(256) void prep_big(
    const float* __restrict__ x, const float* __restrict__ kin,
    const float* __restrict__ af,
    u16* __restrict__ xh, u16* __restrict__ kinh, u16* __restrict__ kinl,
    u16* __restrict__ ab) {
  int i = blockIdx.x * 256 + threadIdx.x;              // 4M threads exact
  xh[i] = f2b(x[i]);
  float v = kin[i];
  u16 hh = f2b(v);
  kinh[i] = hh;
  kinl[i] = f2b(v - b2f(hh));
  ab[i] = f2b(af[i]);                                  // B*N*N == 4M
}

// ---------------- tiled weight transposes (r3 verbatim) ---------------------
__global__ __launch_bounds__(256) void prep_wt(
    const float* __restrict__ Wq, const float* __restrict__ Wkv,
    const float* __restrict__ Wp,
    u16* __restrict__ WqT, u16* __restrict__ WkvTh, u16* __restrict__ WkvTl,
    u16* __restrict__ WpTh, u16* __restrict__ WpTl) {
  __shared__ float tile[64][65];
  int id = blockIdx.x;
  const float* src; int srcld; u16 *dh, *dl; int ot0, it0;
  if (id < 256)      { src = Wq;  srcld = 1024; dh = WqT;   dl = nullptr;
                       ot0 = (id >> 4) * 64; it0 = (id & 15) * 64; }
  else if (id < 768) { id -= 256; src = Wkv; srcld = 2048; dh = WkvTh; dl = WkvTl;
                       ot0 = (id >> 4) * 64; it0 = (id & 15) * 64; }
  else               { id -= 768; src = Wp;  srcld = 1024; dh = WpTh;  dl = WpTl;
                       ot0 = (id >> 4) * 64; it0 = (id & 15) * 64; }
  const int tr = threadIdx.x >> 4;          // 0..15
  const int tc = (threadIdx.x & 15) * 4;    // 0..60
  #pragma unroll
  for (int rr = 0; rr < 4; ++rr) {
    const int r = rr * 16 + tr;
    f32x4 v = *(const f32x4*)&src[(size_t)(it0 + r) * srcld + ot0 + tc];
    tile[r][tc] = v[0]; tile[r][tc + 1] = v[1];
    tile[r][tc + 2] = v[2]; tile[r][tc + 3] = v[3];
  }
  __syncthreads();
  #pragma unroll
  for (int rr = 0; rr < 4; ++rr) {
    const int o = rr * 16 + tr;
    u16x4 hv, lv;
    #pragma unroll
    for (int j = 0; j < 4; ++j) {
      float w = tile[tc + j][o];
      u16 hh = f2b(w);
      hv[j] = hh; lv[j] = f2b(w - b2f(hh));
    }
    const size_t off = (size_t)(ot0 + o) * 1024 + it0 + tc;
    *(u16x4*)(dh + off) = hv;
    if (dl) *(u16x4*)(dl + off) = lv;
  }
}

// ---------------- plain bf16 GEMM 64x128 tile -> q bf16 (r3 verbatim) -------
__global__ __launch_bounds__(256) void gemm_q(
    const u16* __restrict__ A, const u16* __restrict__ Bt, u16* __restrict__ dsth) {
  constexpr int K = 1024;
  __shared__ u16 As[64 * 32];
  __shared__ u16 Bs[128 * 32];
  const int tid = threadIdx.x;
  const int wave = tid >> 6, lane = tid & 63;
  const int l15 = lane & 15, l4 = lane >> 4;
  const int m0 = blockIdx.x * 64, n0 = blockIdx.y * 128;
  const int wr = wave >> 1, wc = wave & 1;
  const int srow = tid >> 2, scol = (tid & 3) * 8;
  f32x4 acc[2][4] = {};
  const u16* gA  = A  + (size_t)(m0 + srow) * K + scol;
  const u16* gB0 = Bt + (size_t)(n0 + srow) * K + scol;
  const u16* gB1 = Bt + (size_t)(n0 + 64 + srow) * K + scol;
  for (int kt = 0; kt < K; kt += 32) {
    __syncthreads();
    __builtin_amdgcn_global_load_lds((gptr_t)(gA  + kt), (lptr_t)(As + wave * 512), 16, 0, 0);
    __builtin_amdgcn_global_load_lds((gptr_t)(gB0 + kt), (lptr_t)(Bs + wave * 512), 16, 0, 0);
    __builtin_amdgcn_global_load_lds((gptr_t)(gB1 + kt), (lptr_t)(Bs + 2048 + wave * 512), 16, 0, 0);
    __syncthreads();
    bf16x8 af[2], bf_[4];
    #pragma unroll
    for (int i = 0; i < 2; ++i)
      af[i] = *(const bf16x8*)(As + (wr * 32 + i * 16 + l15) * 32 + l4 * 8);
    #pragma unroll
    for (int i = 0; i < 4; ++i)
      bf_[i] = *(const bf16x8*)(Bs + (wc * 64 + i * 16 + l15) * 32 + l4 * 8);
    #pragma unroll
    for (int mi = 0; mi < 2; ++mi)
      #pragma unroll
      for (int ni = 0; ni < 4; ++ni)
        acc[mi][ni] = __builtin_amdgcn_mfma_f32_16x16x32_bf16(af[mi], bf_[ni], acc[mi][ni], 0, 0, 0);
  }
  #pragma unroll
  for (int mi = 0; mi < 2; ++mi)
    #pragma unroll
    for (int ni = 0; ni < 4; ++ni)
      #pragma unroll
      for (int r = 0; r < 4; ++r) {
        const int grow = m0 + wr * 32 + mi * 16 + l4 * 4 + r;   // b*N+n
        const int gcol = n0 + wc * 64 + ni * 16 + l15;          // h*64+d
        const int bb = grow >> 10, n = grow & 1023, hh = gcol >> 6, d = gcol & 63;
        dsth[(((size_t)(bb * Hh + hh)) * Nn + n) * HD + d] = f2b(acc[mi][ni][r]);
      }
}

// ------------- plain bf16 KV GEMM 64x128 (r3 gemm3<0> minus low terms) ------
__global__ __launch_bounds__(256) void gemm_kv(
    const u16* __restrict__ Ah, const u16* __restrict__ Bh,
    float* __restrict__ dstf, u16* __restrict__ dsth_k, u16* __restrict__ dsth_v) {
  constexpr int K = 1024;
  __shared__ u16 sAh[64 * 32];
  __shared__ u16 sBh[128 * 32];
  const int tid = threadIdx.x;
  const int wave = tid >> 6, lane = tid & 63;
  const int l15 = lane & 15, l4 = lane >> 4;
  const int m0 = blockIdx.x * 64, n0 = blockIdx.y * 128;
  const int wr = wave >> 1, wc = wave & 1;
  const int srow = tid >> 2, scol = (tid & 3) * 8;
  f32x4 acc[2][4] = {};
  const u16* gAh  = Ah + (size_t)(m0 + srow) * K + scol;
  const u16* gBh0 = Bh + (size_t)(n0 + srow) * K + scol;
  const u16* gBh1 = Bh + (size_t)(n0 + 64 + srow) * K + scol;
  for (int kt = 0; kt < K; kt += 32) {
    __syncthreads();
    __builtin_amdgcn_global_load_lds((gptr_t)(gAh  + kt), (lptr_t)(sAh + wave * 512), 16, 0, 0);
    __builtin_amdgcn_global_load_lds((gptr_t)(gBh0 + kt), (lptr_t)(sBh + wave * 512), 16, 0, 0);
    __builtin_amdgcn_global_load_lds((gptr_t)(gBh1 + kt), (lptr_t)(sBh + 2048 + wave * 512), 16, 0, 0);
    __syncthreads();
    bf16x8 fah[2], fbh[4];
    #pragma unroll
    for (int i = 0; i < 2; ++i)
      fah[i] = *(const bf16x8*)(sAh + (wr * 32 + i * 16 + l15) * 32 + l4 * 8);
    #pragma unroll
    for (int i = 0; i < 4; ++i)
      fbh[i] = *(const bf16x8*)(sBh + (wc * 64 + i * 16 + l15) * 32 + l4 * 8);
    #pragma unroll
    for (int mi = 0; mi < 2; ++mi)
      #pragma unroll
      for (int ni = 0; ni < 4; ++ni)
        acc[mi][ni] = __builtin_amdgcn_mfma_f32_16x16x32_bf16(fah[mi], fbh[ni], acc[mi][ni], 0, 0, 0);
  }
  #pragma unroll
  for (int mi = 0; mi < 2; ++mi)
    #pragma unroll
    for (int ni = 0; ni < 4; ++ni)
      #pragma unroll
      for (int r = 0; r < 4; ++r) {
        const int grow = m0 + wr * 32 + mi * 16 + l4 * 4 + r;
        const int gcol = n0 + wc * 64 + ni * 16 + l15;
        const float v = acc[mi][ni][r];
        const int bb = grow >> 10, n = grow & 1023;
        if (n0 < 1024) {          // k columns (uniform per block)
          const int hh = gcol >> 6, d = gcol & 63;
          dsth_k[(((size_t)(bb * Hh + hh)) * Nn + n) * HD + d] = f2b(v);
        } else {                  // v columns
          const int col = gcol - 1024;
          const int hh = col >> 6, d = col & 63;
          const size_t o = (((size_t)(bb * Hh + hh)) * HD + d) * Nn + n;
          dstf[o] = v;
          dsth_v[o] = f2b(v);
        }
      }
}

// ---------------- SumV[b][h][d] = sum_m v[m][d] (r3 verbatim, reads vtf) ----
__global__ __launch_bounds__(256) void sumv_kernel(const float* __restrict__ vtf,
                                                   float* __restrict__ sv) {
  const int bh = blockIdx.x >> 2, d16 = blockIdx.x & 3;
  const int t = threadIdx.x;
  const int d = d16 * 16 + (t >> 4), part = t & 15;
  const float* src = vtf + ((size_t)bh * HD + d) * Nn + part * 64;
  float s = 0.f;
  #pragma unroll
  for (int i = 0; i < 64; i += 4) {
    f32x4 v = *(const f32x4*)(src + i);
    s += v[0] + v[1] + v[2] + v[3];
  }
  s += __shfl_xor(s, 1, 64);
  s += __shfl_xor(s, 2, 64);
  s += __shfl_xor(s, 4, 64);
  s += __shfl_xor(s, 8, 64);
  if (part == 0) sv[(size_t)bh * HD + d] = s;
}

// ---------------- fused double-softmax attention (r3 verbatim) --------------
__global__ __launch_bounds__(256, 4) void attn_kernel(
    const u16* __restrict__ qb, const u16* __restrict__ kb,
    const u16* __restrict__ vtb, const float* __restrict__ sv,
    const u16* __restrict__ ab, u16* __restrict__ aoh, u16* __restrict__ aol) {
  __shared__ u16 p_lds[2][32 * 128];        // 16 KB, XOR-swizzled cols
  __shared__ float Lp_lds[4][32];
  __shared__ float L_arr[32];
  __shared__ float Ep_arr[32];

  const int tid = threadIdx.x;
  const int wave = tid >> 6, lane = tid & 63;
  const int l15 = lane & 15, l4 = lane >> 4;
  const int bid = (blockIdx.x & 7) * 256 + (blockIdx.x >> 3);   // XCD chunking
  const int qt = bid & 31, h = (bid >> 5) & 15, b = bid >> 9;
  const size_t bh = (size_t)(b * Hh + h);
  const u16* qg = qb + (bh * Nn + qt * 32) * HD;
  const u16* kg = kb + bh * Nn * HD;
  const u16* vg = vtb + bh * HD * Nn;

  // q fragments for both q-tiles
  bf16x8 qf[2][2];
  #pragma unroll
  for (int t2 = 0; t2 < 2; ++t2)
    #pragma unroll
    for (int ks = 0; ks < 2; ++ks)
      qf[t2][ks] = *(const bf16x8*)(qg + (t2 * 16 + l15) * HD + ks * 32 + l4 * 8);

  // ---- pass 1: L[q] = sum_m exp(s/8), prefetched K chain ----
  float Lp[2][4] = {};
  const u16* kbase = kg + (size_t)(wave * 32 + l15) * HD + l4 * 8;
  bf16x8 kc0 = *(const bf16x8*)kbase;
  bf16x8 kc1 = *(const bf16x8*)(kbase + 32);
  #pragma unroll
  for (int j = 0; j < 16; ++j) {
    bf16x8 kn0, kn1;
    if (j < 15) {
      const u16* kr = kbase + (size_t)((((j + 1) >> 1) << 7) + (((j + 1) & 1) << 4)) * HD;
      kn0 = *(const bf16x8*)kr;
      kn1 = *(const bf16x8*)(kr + 32);
    }
    f32x4 s0 = {}, s1 = {};
    s0 = __builtin_amdgcn_mfma_f32_16x16x32_bf16(qf[0][0], kc0, s0, 0, 0, 0);
    s0 = __builtin_amdgcn_mfma_f32_16x16x32_bf16(qf[0][1], kc1, s0, 0, 0, 0);
    s1 = __builtin_amdgcn_mfma_f32_16x16x32_bf16(qf[1][0], kc0, s1, 0, 0, 0);
    s1 = __builtin_amdgcn_mfma_f32_16x16x32_bf16(qf[1][1], kc1, s1, 0, 0, 0);
    #pragma unroll
    for (int r = 0; r < 4; ++r) {
      Lp[0][r] += __expf(s0[r] * SCALE);
      Lp[1][r] += __expf(s1[r] * SCALE);
    }
    kc0 = kn0; kc1 = kn1;
  }
  #pragma unroll
  for (int t2 = 0; t2 < 2; ++t2)
    #pragma unroll
    for (int r = 0; r < 4; ++r) {
      float v = Lp[t2][r];
      v += __shfl_xor(v, 1, 64); v += __shfl_xor(v, 2, 64);
      v += __shfl_xor(v, 4, 64); v += __shfl_xor(v, 8, 64);
      if (l15 == 0) Lp_lds[wave][t2 * 16 + l4 * 4 + r] = v;
    }
  __syncthreads();
  if (tid < 32) L_arr[tid] = Lp_lds[0][tid] + Lp_lds[1][tid] + Lp_lds[2][tid] + Lp_lds[3][tid];
  __syncthreads();
  float nl[2][4];
  #pragma unroll
  for (int t2 = 0; t2 < 2; ++t2)
    #pragma unroll
    for (int r = 0; r < 4; ++r)
      nl[t2][r] = -__logf(L_arr[t2 * 16 + l4 * 4 + r]);

  // ---- pass 2 ----
  const int qB = tid >> 3;                   // 0..31 (fixed per thread)
  const int mB = (tid & 7) << 4;
  const u16* agq = ab + ((size_t)b * Nn + qt * 32 + qB) * Nn + mB;
  const int swzB = (qB & 7) << 3;
  float eacc = 0.f;
  f32x4 oacc[2] = {};

  bf16x8 kcur0 = *(const bf16x8*)kbase;                 // mt=0, cf=0
  bf16x8 kcur1 = *(const bf16x8*)(kbase + 32);
  bf16x8 kcur2 = *(const bf16x8*)(kbase + 16 * HD);     // mt=0, cf=1
  bf16x8 kcur3 = *(const bf16x8*)(kbase + 16 * HD + 32);

  for (int mt = 0; mt < 8; ++mt) {
    u16* pb = p_lds[mt & 1];
    // --- issue all loads consumed later this iteration / next iteration ---
    bf16x8 kn0, kn1, kn2, kn3;
    if (mt < 7) {
      const u16* kr = kbase + (size_t)(mt + 1) * 128 * HD;
      kn0 = *(const bf16x8*)kr;
      kn1 = *(const bf16x8*)(kr + 32);
      kn2 = *(const bf16x8*)(kr + 16 * HD);
      kn3 = *(const bf16x8*)(kr + 16 * HD + 32);
    }
    bf16x8 av0 = *(const bf16x8*)(agq + (mt << 7));
    bf16x8 av1 = *(const bf16x8*)(agq + (mt << 7) + 8);
    bf16x8 vf[4];
    #pragma unroll
    for (int k2 = 0; k2 < 4; ++k2)
      vf[k2] = *(const bf16x8*)(vg + (size_t)(wave * 16 + l15) * Nn + (mt << 7) + k2 * 32 + l4 * 8);

    // --- stage A: scores -> p (bf16) into swizzled LDS ---
    #pragma unroll
    for (int cf = 0; cf < 2; ++cf) {
      bf16x8 ka = cf ? kcur2 : kcur0;
      bf16x8 kbv = cf ? kcur3 : kcur1;
      f32x4 s0 = {}, s1 = {};
      s0 = __builtin_amdgcn_mfma_f32_16x16x32_bf16(qf[0][0], ka, s0, 0, 0, 0);
      s0 = __builtin_amdgcn_mfma_f32_16x16x32_bf16(qf[0][1], kbv, s0, 0, 0, 0);
      s1 = __builtin_amdgcn_mfma_f32_16x16x32_bf16(qf[1][0], ka, s1, 0, 0, 0);
      s1 = __builtin_amdgcn_mfma_f32_16x16x32_bf16(qf[1][1], kbv, s1, 0, 0, 0);
      const int mloc = wave * 32 + cf * 16 + l15;
      #pragma unroll
      for (int r = 0; r < 4; ++r) {
        const int q0 = l4 * 4 + r;
        const int q1 = 16 + q0;
        pb[q0 * 128 + (mloc ^ ((q0 & 7) << 3))] = f2b(__expf(fmaf(s0[r], SCALE, nl[0][r])));
        pb[q1 * 128 + (mloc ^ ((q1 & 7) << 3))] = f2b(__expf(fmaf(s1[r], SCALE, nl[1][r])));
      }
    }
    kcur0 = kn0; kcur1 = kn1; kcur2 = kn2; kcur3 = kn3;
    __syncthreads();   // p ready

    // --- stage B: delta = expm1(p*a) ~ poly, rewrite in place ---
    {
      u16* prow = pb + qB * 128;
      bf16x8 p0 = *(const bf16x8*)(prow + (mB ^ swzB));
      bf16x8 p1 = *(const bf16x8*)(prow + ((mB + 8) ^ swzB));
      bf16x8 d0, d1;
      #pragma unroll
      for (int j = 0; j < 8; ++j) {
        const float z = b2f((u16)p0[j]) * b2f((u16)av0[j]);
        const float t = fmaf(z, 0.16666667f, 0.5f);
        const float dl = fmaf(z * z, t, z);
        eacc += dl;
        d0[j] = (short)f2b(dl);
      }
      #pragma unroll
      for (int j = 0; j < 8; ++j) {
        const float z = b2f((u16)p1[j]) * b2f((u16)av1[j]);
        const float t = fmaf(z, 0.16666667f, 0.5f);
        const float dl = fmaf(z * z, t, z);
        eacc += dl;
        d1[j] = (short)f2b(dl);
      }
      *(bf16x8*)(prow + (mB ^ swzB)) = d0;
      *(bf16x8*)(prow + ((mB + 8) ^ swzB)) = d1;
    }
    __syncthreads();   // deltas ready

    // --- stage C: PV MFMA ---
    #pragma unroll
    for (int t2 = 0; t2 < 2; ++t2)
      #pragma unroll
      for (int k2 = 0; k2 < 4; ++k2) {
        const int row = t2 * 16 + l15;
        bf16x8 df = *(const bf16x8*)(pb + row * 128 + ((k2 * 32 + l4 * 8) ^ ((row & 7) << 3)));
        oacc[t2] = __builtin_amdgcn_mfma_f32_16x16x32_bf16(df, vf[k2], oacc[t2], 0, 0, 0);
      }
  }

  // ---- Ep reduce + epilogue ----
  eacc += __shfl_xor(eacc, 1, 64);
  eacc += __shfl_xor(eacc, 2, 64);
  eacc += __shfl_xor(eacc, 4, 64);
  if ((tid & 7) == 0) Ep_arr[qB] = eacc;
  __syncthreads();
  {
    const int d = wave * 16 + l15;
    const float svd = sv[bh * HD + d];
    #pragma unroll
    for (int t2 = 0; t2 < 2; ++t2)
      #pragma unroll
      for (int r = 0; r < 4; ++r) {
        const int row = t2 * 16 + l4 * 4 + r;
        const float E = 1024.0f + Ep_arr[row];
        const float ov = (svd + oacc[t2][r]) / E;
        const int n = qt * 32 + row;
        const size_t oi = ((size_t)b * Nn + n) * Cc + h * HD + d;
        const u16 hi = f2b(ov);
        aoh[oi] = hi;
        aol[oi] = f2b(ov - b2f(hi));
      }
  }
}

// ---------------- proj GEMM 64x128 + bias (r3 gemm3<1> minus low terms) -----
__global__ __launch_bounds__(256) void gemm_proj(
    const u16* __restrict__ Ah, const u16* __restrict__ Bh,
    const float* __restrict__ bias, float* __restrict__ dstf) {
  constexpr int K = 1024;
  __shared__ u16 As[64 * 32];
  __shared__ u16 Bs[128 * 32];
  const int tid = threadIdx.x;
  const int wave = tid >> 6, lane = tid & 63;
  const int l15 = lane & 15, l4 = lane >> 4;
  const int m0 = blockIdx.x * 64, n0 = blockIdx.y * 128;
  const int wr = wave >> 1, wc = wave & 1;
  const int srow = tid >> 2, scol = (tid & 3) * 8;
  f32x4 acc[2][4] = {};
  const u16* gA  = Ah + (size_t)(m0 + srow) * K + scol;
  const u16* gB0 = Bh + (size_t)(n0 + srow) * K + scol;
  const u16* gB1 = Bh + (size_t)(n0 + 64 + srow) * K + scol;
  for (int kt = 0; kt < K; kt += 32) {
    __syncthreads();
    __builtin_amdgcn_global_load_lds((gptr_t)(gA  + kt), (lptr_t)(As + wave * 512), 16, 0, 0);
    __builtin_amdgcn_global_load_lds((gptr_t)(gB0 + kt), (lptr_t)(Bs + wave * 512), 16, 0, 0);
    __builtin_amdgcn_global_load_lds((gptr_t)(gB1 + kt), (lptr_t)(Bs + 2048 + wave * 512), 16, 0, 0);
    __syncthreads();
    bf16x8 af[2], bf_[4];
    #pragma unroll
    for (int i = 0; i < 2; ++i)
      af[i] = *(const bf16x8*)(As + (wr * 32 + i * 16 + l15) * 32 + l4 * 8);
    #pragma unroll
    for (int i = 0; i < 4; ++i)
      bf_[i] = *(const bf16x8*)(Bs + (wc * 64 + i * 16 + l15) * 32 + l4 * 8);
    #pragma unroll
    for (int mi = 0; mi < 2; ++mi)
      #pragma unroll
      for (int ni = 0; ni < 4; ++ni)
        acc[mi][ni] = __builtin_amdgcn_mfma_f32_16x16x32_bf16(af[mi], bf_[ni], acc[mi][ni], 0, 0, 0);
  }
  #pragma unroll
  for (int mi = 0; mi < 2; ++mi)
    #pragma unroll
    for (int ni = 0; ni < 4; ++ni)
      #pragma unroll
      for (int r = 0; r < 4; ++r) {
        const int grow = m0 + wr * 32 + mi * 16 + l4 * 4 + r;
        const int gcol = n0 + wc * 64 + ni * 16 + l15;
        dstf[(size_t)grow * Cc + gcol] = acc[mi][ni][r] + bias[gcol];
      }
}

// ---------------------------------------------------------------------------
extern "C" void kernel_launch(void* const* d_in, const int* in_sizes, int n_in,
                              void* d_out, int out_size, void* d_ws, size_t ws_size,
                              hipStream_t stream) {
  (void)in_sizes; (void)n_in; (void)out_size; (void)ws_size;
  const float* x   = (const float*)d_in[0];
  const float* kin = (const float*)d_in[1];
  const float* af  = (const float*)d_in[2];
  const float* Wq  = (const float*)d_in[3];
  const float* Wkv = (const float*)d_in[4];
  const float* Wp  = (const float*)d_in[5];
  const float* bp  = (const float*)d_in[6];
  float* out = (float*)d_out;

  char* w = (char*)d_ws;
  auto take = [&](size_t bytes) { char* p = w; w += (bytes + 255) & ~(size_t)255; return p; };
  u16* WqT    = (u16*)take(2097152);
  u16* WkvTh  = (u16*)take(4194304);
  u16* WkvTl  = (u16*)take(4194304);
  u16* WpTh   = (u16*)take(2097152);
  u16* WpTl   = (u16*)take(2097152);
  u16* xh     = (u16*)take(8388608);
  u16* kinh   = (u16*)take(8388608);
  u16* kinl   = (u16*)take(8388608);
  u16* ab     = (u16*)take(8388608);
  u16* qb     = (u16*)take(8388608);
  u16* kb     = (u16*)take(8388608);
  u16* vtb    = (u16*)take(8388608);
  float* vtf  = (float*)take(16777216);
  float* sv   = (float*)take(16384);
  u16* aoh    = (u16*)take(8388608);
  u16* aol    = (u16*)take(8388608);

  prep_big<<<dim3(16384), dim3(256), 0, stream>>>(x, kin, af, xh, kinh, kinl, ab);
  prep_wt<<<dim3(1024), dim3(256), 0, stream>>>(Wq, Wkv, Wp, WqT, WkvTh, WkvTl, WpTh, WpTl);

  gemm_q<<<dim3(64, 8), dim3(256), 0, stream>>>(xh, WqT, qb);
  gemm_kv<<<dim3(64, 16), dim3(256), 0, stream>>>(kinh, WkvTh, vtf, kb, vtb);
  sumv_kernel<<<dim3(256), dim3(256), 0, stream>>>(vtf, sv);
  attn_kernel<<<dim3(2048), dim3(256), 0, stream>>>(qb, kb, vtb, sv, ab, aoh, aol);
  gemm_proj<<<dim3(64, 8), dim3(256), 0, stream>>>(aoh, WpTh, bp, out);
}

// Round 6
// 208.414 us; speedup vs baseline: 1.8095x; 1.1636x over previous
//
#include <hip/hip_runtime.h>
#include <cmath>

// ---------------------------------------------------------------------------
// CrossAttention: B=4, N=1024, C=1024, H=16, HD=64
//   q = x@Wq ; kv = k_in@Wkv ; p = softmax(q k^T /8); z = p*a; w = softmax(z)
//   out = (w@v)@Wproj + b
// Numerics (confirmed r5): plain bf16 GEMMs everywhere; PV centered:
//   out = (SumV + sum expm1(z)*v)/E, z = c*a/L, c = exp(s/8).
// v6: attn ONE-PASS — c kept packed in 64 VGPRs via v_cvt_pk_bf16_f32
// (T12 idiom); pass 2 has NO score MFMAs / K loads / exp / log; 1/L folded
// into stage B; a read as f32. Rest = round-5 verbatim.
// ---------------------------------------------------------------------------

#define Bb 4
#define Nn 1024
#define Cc 1024
#define Hh 16
#define HD 64
static constexpr float SCALE = 0.125f;

typedef unsigned short u16;
typedef short bf16x8 __attribute__((ext_vector_type(8)));
typedef float f32x4 __attribute__((ext_vector_type(4)));
typedef unsigned short u16x4 __attribute__((ext_vector_type(4)));
typedef __attribute__((address_space(1))) const void* gptr_t;
typedef __attribute__((address_space(3))) void* lptr_t;

__device__ __forceinline__ u16 f2b(float f) {
  union { float f; unsigned u; } x; x.f = f;
  unsigned u = x.u;
  return (u16)((u + 0x7FFFu + ((u >> 16) & 1u)) >> 16);
}
__device__ __forceinline__ float b2f(u16 h) {
  union { unsigned u; float f; } x; x.u = ((unsigned)h) << 16;
  return x.f;
}

// ---------------- prep: bf16 casts of x, k_in -------------------------------
__global__ __launch_bounds__(256) void prep_big(
    const float* __restrict__ x, const float* __restrict__ kin,
    u16* __restrict__ xh, u16* __restrict__ kinh) {
  int i = blockIdx.x * 256 + threadIdx.x;              // 4M threads exact
  xh[i] = f2b(x[i]);
  kinh[i] = f2b(kin[i]);
}

// ---------------- tiled weight transposes (coalesced both sides) ------------
__global__ __launch_bounds__(256) void prep_wt(
    const float* __restrict__ Wq, const float* __restrict__ Wkv,
    const float* __restrict__ Wp,
    u16* __restrict__ WqT, u16* __restrict__ WkvTh, u16* __restrict__ WpTh) {
  __shared__ float tile[64][65];
  int id = blockIdx.x;
  const float* src; int srcld; u16* dh; int ot0, it0;
  if (id < 256)      { src = Wq;  srcld = 1024; dh = WqT;
                       ot0 = (id >> 4) * 64; it0 = (id & 15) * 64; }
  else if (id < 768) { id -= 256; src = Wkv; srcld = 2048; dh = WkvTh;
                       ot0 = (id >> 4) * 64; it0 = (id & 15) * 64; }
  else               { id -= 768; src = Wp;  srcld = 1024; dh = WpTh;
                       ot0 = (id >> 4) * 64; it0 = (id & 15) * 64; }
  const int tr = threadIdx.x >> 4;          // 0..15
  const int tc = (threadIdx.x & 15) * 4;    // 0..60
  #pragma unroll
  for (int rr = 0; rr < 4; ++rr) {
    const int r = rr * 16 + tr;
    f32x4 v = *(const f32x4*)&src[(size_t)(it0 + r) * srcld + ot0 + tc];
    tile[r][tc] = v[0]; tile[r][tc + 1] = v[1];
    tile[r][tc + 2] = v[2]; tile[r][tc + 3] = v[3];
  }
  __syncthreads();
  #pragma unroll
  for (int rr = 0; rr < 4; ++rr) {
    const int o = rr * 16 + tr;
    u16x4 hv;
    #pragma unroll
    for (int j = 0; j < 4; ++j) hv[j] = f2b(tile[tc + j][o]);
    *(u16x4*)(dh + (size_t)(ot0 + o) * 1024 + it0 + tc) = hv;
  }
}

// ---------------- plain bf16 GEMM 64x128 tile -> q bf16 (r5 verbatim) -------
__global__ __launch_bounds__(256) void gemm_q(
    const u16* __restrict__ A, const u16* __restrict__ Bt, u16* __restrict__ dsth) {
  constexpr int K = 1024;
  __shared__ u16 As[64 * 32];
  __shared__ u16 Bs[128 * 32];
  const int tid = threadIdx.x;
  const int wave = tid >> 6, lane = tid & 63;
  const int l15 = lane & 15, l4 = lane >> 4;
  const int m0 = blockIdx.x * 64, n0 = blockIdx.y * 128;
  const int wr = wave >> 1, wc = wave & 1;
  const int srow = tid >> 2, scol = (tid & 3) * 8;
  f32x4 acc[2][4] = {};
  const u16* gA  = A  + (size_t)(m0 + srow) * K + scol;
  const u16* gB0 = Bt + (size_t)(n0 + srow) * K + scol;
  const u16* gB1 = Bt + (size_t)(n0 + 64 + srow) * K + scol;
  for (int kt = 0; kt < K; kt += 32) {
    __syncthreads();
    __builtin_amdgcn_global_load_lds((gptr_t)(gA  + kt), (lptr_t)(As + wave * 512), 16, 0, 0);
    __builtin_amdgcn_global_load_lds((gptr_t)(gB0 + kt), (lptr_t)(Bs + wave * 512), 16, 0, 0);
    __builtin_amdgcn_global_load_lds((gptr_t)(gB1 + kt), (lptr_t)(Bs + 2048 + wave * 512), 16, 0, 0);
    __syncthreads();
    bf16x8 af[2], bf_[4];
    #pragma unroll
    for (int i = 0; i < 2; ++i)
      af[i] = *(const bf16x8*)(As + (wr * 32 + i * 16 + l15) * 32 + l4 * 8);
    #pragma unroll
    for (int i = 0; i < 4; ++i)
      bf_[i] = *(const bf16x8*)(Bs + (wc * 64 + i * 16 + l15) * 32 + l4 * 8);
    #pragma unroll
    for (int mi = 0; mi < 2; ++mi)
      #pragma unroll
      for (int ni = 0; ni < 4; ++ni)
        acc[mi][ni] = __builtin_amdgcn_mfma_f32_16x16x32_bf16(af[mi], bf_[ni], acc[mi][ni], 0, 0, 0);
  }
  #pragma unroll
  for (int mi = 0; mi < 2; ++mi)
    #pragma unroll
    for (int ni = 0; ni < 4; ++ni)
      #pragma unroll
      for (int r = 0; r < 4; ++r) {
        const int grow = m0 + wr * 32 + mi * 16 + l4 * 4 + r;   // b*N+n
        const int gcol = n0 + wc * 64 + ni * 16 + l15;          // h*64+d
        const int bb = grow >> 10, n = grow & 1023, hh = gcol >> 6, d = gcol & 63;
        dsth[(((size_t)(bb * Hh + hh)) * Nn + n) * HD + d] = f2b(acc[mi][ni][r]);
      }
}

// ------------- plain bf16 KV GEMM 64x128 (r5 verbatim) ----------------------
__global__ __launch_bounds__(256) void gemm_kv(
    const u16* __restrict__ Ah, const u16* __restrict__ Bh,
    float* __restrict__ dstf, u16* __restrict__ dsth_k, u16* __restrict__ dsth_v) {
  constexpr int K = 1024;
  __shared__ u16 sAh[64 * 32];
  __shared__ u16 sBh[128 * 32];
  const int tid = threadIdx.x;
  const int wave = tid >> 6, lane = tid & 63;
  const int l15 = lane & 15, l4 = lane >> 4;
  const int m0 = blockIdx.x * 64, n0 = blockIdx.y * 128;
  const int wr = wave >> 1, wc = wave & 1;
  const int srow = tid >> 2, scol = (tid & 3) * 8;
  f32x4 acc[2][4] = {};
  const u16* gAh  = Ah + (size_t)(m0 + srow) * K + scol;
  const u16* gBh0 = Bh + (size_t)(n0 + srow) * K + scol;
  const u16* gBh1 = Bh + (size_t)(n0 + 64 + srow) * K + scol;
  for (int kt = 0; kt < K; kt += 32) {
    __syncthreads();
    __builtin_amdgcn_global_load_lds((gptr_t)(gAh  + kt), (lptr_t)(sAh + wave * 512), 16, 0, 0);
    __builtin_amdgcn_global_load_lds((gptr_t)(gBh0 + kt), (lptr_t)(sBh + wave * 512), 16, 0, 0);
    __builtin_amdgcn_global_load_lds((gptr_t)(gBh1 + kt), (lptr_t)(sBh + 2048 + wave * 512), 16, 0, 0);
    __syncthreads();
    bf16x8 fah[2], fbh[4];
    #pragma unroll
    for (int i = 0; i < 2; ++i)
      fah[i] = *(const bf16x8*)(sAh + (wr * 32 + i * 16 + l15) * 32 + l4 * 8);
    #pragma unroll
    for (int i = 0; i < 4; ++i)
      fbh[i] = *(const bf16x8*)(sBh + (wc * 64 + i * 16 + l15) * 32 + l4 * 8);
    #pragma unroll
    for (int mi = 0; mi < 2; ++mi)
      #pragma unroll
      for (int ni = 0; ni < 4; ++ni)
        acc[mi][ni] = __builtin_amdgcn_mfma_f32_16x16x32_bf16(fah[mi], fbh[ni], acc[mi][ni], 0, 0, 0);
  }
  #pragma unroll
  for (int mi = 0; mi < 2; ++mi)
    #pragma unroll
    for (int ni = 0; ni < 4; ++ni)
      #pragma unroll
      for (int r = 0; r < 4; ++r) {
        const int grow = m0 + wr * 32 + mi * 16 + l4 * 4 + r;
        const int gcol = n0 + wc * 64 + ni * 16 + l15;
        const float v = acc[mi][ni][r];
        const int bb = grow >> 10, n = grow & 1023;
        if (n0 < 1024) {          // k columns (uniform per block)
          const int hh = gcol >> 6, d = gcol & 63;
          dsth_k[(((size_t)(bb * Hh + hh)) * Nn + n) * HD + d] = f2b(v);
        } else {                  // v columns
          const int col = gcol - 1024;
          const int hh = col >> 6, d = col & 63;
          const size_t o = (((size_t)(bb * Hh + hh)) * HD + d) * Nn + n;
          dstf[o] = v;
          dsth_v[o] = f2b(v);
        }
      }
}

// ---------------- SumV[b][h][d] = sum_m v[m][d] (r5 verbatim) ---------------
__global__ __launch_bounds__(256) void sumv_kernel(const float* __restrict__ vtf,
                                                   float* __restrict__ sv) {
  const int bh = blockIdx.x >> 2, d16 = blockIdx.x & 3;
  const int t = threadIdx.x;
  const int d = d16 * 16 + (t >> 4), part = t & 15;
  const float* src = vtf + ((size_t)bh * HD + d) * Nn + part * 64;
  float s = 0.f;
  #pragma unroll
  for (int i = 0; i < 64; i += 4) {
    f32x4 v = *(const f32x4*)(src + i);
    s += v[0] + v[1] + v[2] + v[3];
  }
  s += __shfl_xor(s, 1, 64);
  s += __shfl_xor(s, 2, 64);
  s += __shfl_xor(s, 4, 64);
  s += __shfl_xor(s, 8, 64);
  if (part == 0) sv[(size_t)bh * HD + d] = s;
}

// ---------------- fused double-softmax attention (v6: one-pass) -------------
// block = 32 q-rows, 4 waves, grid 2048. Pass 1 computes c=exp(s/8) for all
// 1024 m and keeps it packed bf16 in 64 VGPRs (cvt_pk), accumulating L.
// Pass 2 per mt: unpack c -> swizzled LDS; delta=expm1(c*a/L) in place;
// PV MFMA. No score recompute, no exp/log in pass 2.
__global__ __launch_bounds__(256, 3) void attn_kernel(
    const u16* __restrict__ qb, const u16* __restrict__ kb,
    const u16* __restrict__ vtb, const float* __restrict__ sv,
    const float* __restrict__ af, u16* __restrict__ aoh) {
  __shared__ u16 p_lds[2][32 * 128];        // 16 KB, XOR-swizzled cols
  __shared__ float Lp_lds[4][32];
  __shared__ float L_arr[32];               // holds 1/L
  __shared__ float Ep_arr[32];

  const int tid = threadIdx.x;
  const int wave = tid >> 6, lane = tid & 63;
  const int l15 = lane & 15, l4 = lane >> 4;
  const int bid = (blockIdx.x & 7) * 256 + (blockIdx.x >> 3);   // XCD chunking
  const int qt = bid & 31, h = (bid >> 5) & 15, b = bid >> 9;
  const size_t bh = (size_t)(b * Hh + h);
  const u16* qg = qb + (bh * Nn + qt * 32) * HD;
  const u16* kg = kb + bh * Nn * HD;
  const u16* vg = vtb + bh * HD * Nn;

  // q fragments for both q-tiles
  bf16x8 qf[2][2];
  #pragma unroll
  for (int t2 = 0; t2 < 2; ++t2)
    #pragma unroll
    for (int ks = 0; ks < 2; ++ks)
      qf[t2][ks] = *(const bf16x8*)(qg + (t2 * 16 + l15) * HD + ks * 32 + l4 * 8);

  // ---- pass 1: c = exp(s/8) for all m (kept in regs), L = sum c ----
  // iteration j covers m rows (j>>1)*128 + (j&1)*16 + wave*32 + l15,
  // i.e. j == mt*2 + cf exactly as consumed by pass 2.
  float Lp[2][4] = {};
  unsigned cpk[16][4];                      // [j][r]: lo=tile0, hi=tile1
  const u16* kbase = kg + (size_t)(wave * 32 + l15) * HD + l4 * 8;
  bf16x8 kc0 = *(const bf16x8*)kbase;
  bf16x8 kc1 = *(const bf16x8*)(kbase + 32);
  #pragma unroll
  for (int j = 0; j < 16; ++j) {
    bf16x8 kn0, kn1;
    if (j < 15) {
      const u16* kr = kbase + (size_t)((((j + 1) >> 1) << 7) + (((j + 1) & 1) << 4)) * HD;
      kn0 = *(const bf16x8*)kr;
      kn1 = *(const bf16x8*)(kr + 32);
    }
    f32x4 s0 = {}, s1 = {};
    s0 = __builtin_amdgcn_mfma_f32_16x16x32_bf16(qf[0][0], kc0, s0, 0, 0, 0);
    s0 = __builtin_amdgcn_mfma_f32_16x16x32_bf16(qf[0][1], kc1, s0, 0, 0, 0);
    s1 = __builtin_amdgcn_mfma_f32_16x16x32_bf16(qf[1][0], kc0, s1, 0, 0, 0);
    s1 = __builtin_amdgcn_mfma_f32_16x16x32_bf16(qf[1][1], kc1, s1, 0, 0, 0);
    #pragma unroll
    for (int r = 0; r < 4; ++r) {
      const float e0 = __expf(s0[r] * SCALE);
      const float e1 = __expf(s1[r] * SCALE);
      Lp[0][r] += e0;
      Lp[1][r] += e1;
      asm("v_cvt_pk_bf16_f32 %0, %1, %2" : "=v"(cpk[j][r]) : "v"(e0), "v"(e1));
    }
    kc0 = kn0; kc1 = kn1;
  }
  #pragma unroll
  for (int t2 = 0; t2 < 2; ++t2)
    #pragma unroll
    for (int r = 0; r < 4; ++r) {
      float v = Lp[t2][r];
      v += __shfl_xor(v, 1, 64); v += __shfl_xor(v, 2, 64);
      v += __shfl_xor(v, 4, 64); v += __shfl_xor(v, 8, 64);
      if (l15 == 0) Lp_lds[wave][t2 * 16 + l4 * 4 + r] = v;
    }
  __syncthreads();
  if (tid < 32)
    L_arr[tid] = 1.0f / (Lp_lds[0][tid] + Lp_lds[1][tid] + Lp_lds[2][tid] + Lp_lds[3][tid]);
  __syncthreads();

  // ---- pass 2 ----
  const int qB = tid >> 3;                   // 0..31 (fixed per thread)
  const int mB = (tid & 7) << 4;
  const float* agq = af + ((size_t)b * Nn + qt * 32 + qB) * Nn + mB;
  const int swzB = (qB & 7) << 3;
  const float linv = L_arr[qB];
  float eacc = 0.f;
  f32x4 oacc[2] = {};

  #pragma unroll
  for (int mt = 0; mt < 8; ++mt) {
    u16* pb = p_lds[mt & 1];
    // --- prefetch a (f32) + V for this mt ---
    f32x4 av0 = *(const f32x4*)(agq + (mt << 7));
    f32x4 av1 = *(const f32x4*)(agq + (mt << 7) + 4);
    f32x4 av2 = *(const f32x4*)(agq + (mt << 7) + 8);
    f32x4 av3 = *(const f32x4*)(agq + (mt << 7) + 12);
    bf16x8 vf[4];
    #pragma unroll
    for (int k2 = 0; k2 < 4; ++k2)
      vf[k2] = *(const bf16x8*)(vg + (size_t)(wave * 16 + l15) * Nn + (mt << 7) + k2 * 32 + l4 * 8);

    // --- stage A: unpack register c -> swizzled LDS (no math) ---
    #pragma unroll
    for (int cf = 0; cf < 2; ++cf) {
      const int mloc = wave * 32 + cf * 16 + l15;
      #pragma unroll
      for (int r = 0; r < 4; ++r) {
        const int q0 = l4 * 4 + r;
        const unsigned pk = cpk[mt * 2 + cf][r];
        const int col = mloc ^ ((q0 & 7) << 3);
        pb[q0 * 128 + col] = (u16)pk;
        pb[(q0 + 16) * 128 + col] = (u16)(pk >> 16);
      }
    }
    __syncthreads();   // c ready

    // --- stage B: delta = expm1(c*a/L) ~ poly, rewrite in place ---
    {
      u16* prow = pb + qB * 128;
      bf16x8 p0 = *(const bf16x8*)(prow + (mB ^ swzB));
      bf16x8 p1 = *(const bf16x8*)(prow + ((mB + 8) ^ swzB));
      const float aA[8] = {av0[0], av0[1], av0[2], av0[3], av1[0], av1[1], av1[2], av1[3]};
      const float aB[8] = {av2[0], av2[1], av2[2], av2[3], av3[0], av3[1], av3[2], av3[3]};
      union O8 { unsigned u[4]; bf16x8 v; } dA, dB;
      #pragma unroll
      for (int jj = 0; jj < 4; ++jj) {
        const float z0 = b2f((u16)p0[2 * jj])     * (aA[2 * jj]     * linv);
        const float z1 = b2f((u16)p0[2 * jj + 1]) * (aA[2 * jj + 1] * linv);
        const float d0 = fmaf(z0 * z0, fmaf(z0, 0.16666667f, 0.5f), z0);
        const float d1 = fmaf(z1 * z1, fmaf(z1, 0.16666667f, 0.5f), z1);
        eacc += d0 + d1;
        asm("v_cvt_pk_bf16_f32 %0, %1, %2" : "=v"(dA.u[jj]) : "v"(d0), "v"(d1));
      }
      #pragma unroll
      for (int jj = 0; jj < 4; ++jj) {
        const float z0 = b2f((u16)p1[2 * jj])     * (aB[2 * jj]     * linv);
        const float z1 = b2f((u16)p1[2 * jj + 1]) * (aB[2 * jj + 1] * linv);
        const float d0 = fmaf(z0 * z0, fmaf(z0, 0.16666667f, 0.5f), z0);
        const float d1 = fmaf(z1 * z1, fmaf(z1, 0.16666667f, 0.5f), z1);
        eacc += d0 + d1;
        asm("v_cvt_pk_bf16_f32 %0, %1, %2" : "=v"(dB.u[jj]) : "v"(d0), "v"(d1));
      }
      *(bf16x8*)(prow + (mB ^ swzB)) = dA.v;
      *(bf16x8*)(prow + ((mB + 8) ^ swzB)) = dB.v;
    }
    __syncthreads();   // deltas ready

    // --- stage C: PV MFMA ---
    #pragma unroll
    for (int t2 = 0; t2 < 2; ++t2)
      #pragma unroll
      for (int k2 = 0; k2 < 4; ++k2) {
        const int row = t2 * 16 + l15;
        bf16x8 df = *(const bf16x8*)(pb + row * 128 + ((k2 * 32 + l4 * 8) ^ ((row & 7) << 3)));
        oacc[t2] = __builtin_amdgcn_mfma_f32_16x16x32_bf16(df, vf[k2], oacc[t2], 0, 0, 0);
      }
  }

  // ---- Ep reduce + epilogue ----
  eacc += __shfl_xor(eacc, 1, 64);
  eacc += __shfl_xor(eacc, 2, 64);
  eacc += __shfl_xor(eacc, 4, 64);
  if ((tid & 7) == 0) Ep_arr[qB] = eacc;
  __syncthreads();
  {
    const int d = wave * 16 + l15;
    const float svd = sv[bh * HD + d];
    #pragma unroll
    for (int t2 = 0; t2 < 2; ++t2)
      #pragma unroll
      for (int r = 0; r < 4; ++r) {
        const int row = t2 * 16 + l4 * 4 + r;
        const float E = 1024.0f + Ep_arr[row];
        const float ov = (svd + oacc[t2][r]) / E;
        const int n = qt * 32 + row;
        aoh[((size_t)b * Nn + n) * Cc + h * HD + d] = f2b(ov);
      }
  }
}

// ---------------- proj GEMM 64x128 + bias (r5 verbatim) ---------------------
__global__ __launch_bounds__(256) void gemm_proj(
    const u16* __restrict__ Ah, const u16* __restrict__ Bh,
    const float* __restrict__ bias, float* __restrict__ dstf) {
  constexpr int K = 1024;
  __shared__ u16 As[64 * 32];
  __shared__ u16 Bs[128 * 32];
  const int tid = threadIdx.x;
  const int wave = tid >> 6, lane = tid & 63;
  const int l15 = lane & 15, l4 = lane >> 4;
  const int m0 = blockIdx.x * 64, n0 = blockIdx.y * 128;
  const int wr = wave >> 1, wc = wave & 1;
  const int srow = tid >> 2, scol = (tid & 3) * 8;
  f32x4 acc[2][4] = {};
  const u16* gA  = Ah + (size_t)(m0 + srow) * K + scol;
  const u16* gB0 = Bh + (size_t)(n0 + srow) * K + scol;
  const u16* gB1 = Bh + (size_t)(n0 + 64 + srow) * K + scol;
  for (int kt = 0; kt < K; kt += 32) {
    __syncthreads();
    __builtin_amdgcn_global_load_lds((gptr_t)(gA  + kt), (lptr_t)(As + wave * 512), 16, 0, 0);
    __builtin_amdgcn_global_load_lds((gptr_t)(gB0 + kt), (lptr_t)(Bs + wave * 512), 16, 0, 0);
    __builtin_amdgcn_global_load_lds((gptr_t)(gB1 + kt), (lptr_t)(Bs + 2048 + wave * 512), 16, 0, 0);
    __syncthreads();
    bf16x8 af[2], bf_[4];
    #pragma unroll
    for (int i = 0; i < 2; ++i)
      af[i] = *(const bf16x8*)(As + (wr * 32 + i * 16 + l15) * 32 + l4 * 8);
    #pragma unroll
    for (int i = 0; i < 4; ++i)
      bf_[i] = *(const bf16x8*)(Bs + (wc * 64 + i * 16 + l15) * 32 + l4 * 8);
    #pragma unroll
    for (int mi = 0; mi < 2; ++mi)
      #pragma unroll
      for (int ni = 0; ni < 4; ++ni)
        acc[mi][ni] = __builtin_amdgcn_mfma_f32_16x16x32_bf16(af[mi], bf_[ni], acc[mi][ni], 0, 0, 0);
  }
  #pragma unroll
  for (int mi = 0; mi < 2; ++mi)
    #pragma unroll
    for (int ni = 0; ni < 4; ++ni)
      #pragma unroll
      for (int r = 0; r < 4; ++r) {
        const int grow = m0 + wr * 32 + mi * 16 + l4 * 4 + r;
        const int gcol = n0 + wc * 64 + ni * 16 + l15;
        dstf[(size_t)grow * Cc + gcol] = acc[mi][ni][r] + bias[gcol];
      }
}

// ---------------------------------------------------------------------------
extern "C" void kernel_launch(void* const* d_in, const int* in_sizes, int n_in,
                              void* d_out, int out_size, void* d_ws, size_t ws_size,
                              hipStream_t stream) {
  (void)in_sizes; (void)n_in; (void)out_size; (void)ws_size;
  const float* x   = (const float*)d_in[0];
  const float* kin = (const float*)d_in[1];
  const float* af  = (const float*)d_in[2];
  const float* Wq  = (const float*)d_in[3];
  const float* Wkv = (const float*)d_in[4];
  const float* Wp  = (const float*)d_in[5];
  const float* bp  = (const float*)d_in[6];
  float* out = (float*)d_out;

  char* w = (char*)d_ws;
  auto take = [&](size_t bytes) { char* p = w; w += (bytes + 255) & ~(size_t)255; return p; };
  u16* WqT    = (u16*)take(2097152);
  u16* WkvTh  = (u16*)take(4194304);
  u16* WpTh   = (u16*)take(2097152);
  u16* xh     = (u16*)take(8388608);
  u16* kinh   = (u16*)take(8388608);
  u16* qb     = (u16*)take(8388608);
  u16* kb     = (u16*)take(8388608);
  u16* vtb    = (u16*)take(8388608);
  float* vtf  = (float*)take(16777216);
  float* sv   = (float*)take(16384);
  u16* aoh    = (u16*)take(8388608);

  prep_big<<<dim3(16384), dim3(256), 0, stream>>>(x, kin, xh, kinh);
  prep_wt<<<dim3(1024), dim3(256), 0, stream>>>(Wq, Wkv, Wp, WqT, WkvTh, WpTh);

  gemm_q<<<dim3(64, 8), dim3(256), 0, stream>>>(xh, WqT, qb);
  gemm_kv<<<dim3(64, 16), dim3(256), 0, stream>>>(kinh, WkvTh, vtf, kb, vtb);
  sumv_kernel<<<dim3(256), dim3(256), 0, stream>>>(vtf, sv);
  attn_kernel<<<dim3(2048), dim3(256), 0, stream>>>(qb, kb, vtb, sv, af, aoh);
  gemm_proj<<<dim3(64, 8), dim3(256), 0, stream>>>(aoh, WpTh, bp, out);
}